// Round 1
// baseline (1897.586 us; speedup 1.0000x reference)
//
#include <hip/hip_runtime.h>
#include <cstddef>

#define NUSERS 50000
#define NITEMS 50000
#define NNODES 100000
#define DIM    128
#define NLAYERS 3
#define NEDGES 600000

// ---------------------------------------------------------------------------
// concat user/item embeddings into x = d_out  [N,128]
// ---------------------------------------------------------------------------
__global__ void concat_kernel(const float* __restrict__ ue,
                              const float* __restrict__ ie,
                              float* __restrict__ x) {
    int i = blockIdx.x * blockDim.x + threadIdx.x;      // float4 index
    const int uq = NUSERS * DIM / 4;
    const int tq = NNODES * DIM / 4;
    if (i < tq) {
        float4 v = (i < uq) ? ((const float4*)ue)[i]
                            : ((const float4*)ie)[i - uq];
        ((float4*)x)[i] = v;
    }
}

// ---------------------------------------------------------------------------
// per-edge attention + atomic scatter:  agg[dst] += src_emb * sigmoid(att)
// one 64-lane wave per edge; lane owns 2 floats of the embedding
// ---------------------------------------------------------------------------
__global__ __launch_bounds__(256) void att_scatter_kernel(
        const int* __restrict__ src, const int* __restrict__ dst,
        const float* __restrict__ x, const float* __restrict__ Wa,
        const float* __restrict__ ba, float* __restrict__ agg) {
    const int e = (blockIdx.x * blockDim.x + threadIdx.x) >> 6;
    if (e >= NEDGES) return;
    const int lane = threadIdx.x & 63;

    const int s = src[e];
    const int d = dst[e];

    const float2 se  = *(const float2*)(x + (size_t)s * DIM + lane * 2);
    const float2 de  = *(const float2*)(x + (size_t)d * DIM + lane * 2);
    const float2 was = *(const float2*)(Wa + lane * 2);
    const float2 wad = *(const float2*)(Wa + DIM + lane * 2);

    float p = se.x * was.x + se.y * was.y + de.x * wad.x + de.y * wad.y;
    #pragma unroll
    for (int off = 32; off; off >>= 1) p += __shfl_xor(p, off);

    const float att = 1.0f / (1.0f + expf(-(p + ba[0])));

    float* dest = agg + (size_t)d * DIM + lane * 2;
    atomicAdd(dest,     se.x * att);
    atomicAdd(dest + 1, se.y * att);
}

// ---------------------------------------------------------------------------
// x_new = relu([x || agg] @ Wg + bg)   — in place on x (block owns its rows)
// block = 256 threads, tile = 32 rows; in staged transposed in LDS [k][row];
// each thread computes 4 rows x 4 cols; Wg read from global (L2-resident).
// ---------------------------------------------------------------------------
__global__ __launch_bounds__(256) void gemm_relu_kernel(
        const float* __restrict__ xin, const float* __restrict__ agg,
        const float* __restrict__ Wg,  const float* __restrict__ bg,
        float* __restrict__ xout) {
    __shared__ float in_t[256 * 32];          // [k][row_local]  32 KB

    const int t    = threadIdx.x;
    const int base = blockIdx.x * 32;

    // ---- stage 32 rows x 256 (x row || agg row), transposed into LDS ----
    {
        const int rl  = t >> 3;               // 0..31 row_local
        const int kqb = t & 7;                // float4-index base
        const size_t row = (size_t)(base + rl);
        const float4* xr = (const float4*)(xin + row * DIM);
        const float4* ar = (const float4*)(agg + row * DIM);
        #pragma unroll
        for (int j = 0; j < 8; ++j) {
            const int kq = kqb + j * 8;       // 0..63
            const float4 v = (kq < 32) ? xr[kq] : ar[kq - 32];
            const int k0 = kq * 4;
            in_t[(k0 + 0) * 32 + rl] = v.x;
            in_t[(k0 + 1) * 32 + rl] = v.y;
            in_t[(k0 + 2) * 32 + rl] = v.z;
            in_t[(k0 + 3) * 32 + rl] = v.w;
        }
    }
    __syncthreads();

    const int cg = t & 31;                    // col group: cols cg*4..cg*4+3
    const int rg = t >> 5;                    // 0..7: rows rg*4..rg*4+3

    float4 acc0 = {0,0,0,0}, acc1 = {0,0,0,0}, acc2 = {0,0,0,0}, acc3 = {0,0,0,0};
    const float4* wg4 = (const float4*)Wg;    // [k][32 x float4]

    #pragma unroll 4
    for (int k = 0; k < 256; ++k) {
        const float4 w = wg4[k * 32 + cg];
        const float4 a = *(const float4*)(&in_t[k * 32 + rg * 4]);
        acc0.x += a.x * w.x; acc0.y += a.x * w.y; acc0.z += a.x * w.z; acc0.w += a.x * w.w;
        acc1.x += a.y * w.x; acc1.y += a.y * w.y; acc1.z += a.y * w.z; acc1.w += a.y * w.w;
        acc2.x += a.z * w.x; acc2.y += a.z * w.y; acc2.z += a.z * w.z; acc2.w += a.z * w.w;
        acc3.x += a.w * w.x; acc3.y += a.w * w.y; acc3.z += a.w * w.z; acc3.w += a.w * w.w;
    }

    const float4 bias = ((const float4*)bg)[cg];
    float4 o;
    float4 accs[4] = {acc0, acc1, acc2, acc3};
    #pragma unroll
    for (int r = 0; r < 4; ++r) {
        o.x = fmaxf(accs[r].x + bias.x, 0.0f);
        o.y = fmaxf(accs[r].y + bias.y, 0.0f);
        o.z = fmaxf(accs[r].z + bias.z, 0.0f);
        o.w = fmaxf(accs[r].w + bias.w, 0.0f);
        ((float4*)(xout + (size_t)(base + rg * 4 + r) * DIM))[cg] = o;
    }
}

// ---------------------------------------------------------------------------
extern "C" void kernel_launch(void* const* d_in, const int* in_sizes, int n_in,
                              void* d_out, int out_size, void* d_ws, size_t ws_size,
                              hipStream_t stream) {
    const int*   edge = (const int*)d_in[0];       // [2, E]
    const float* ue   = (const float*)d_in[1];     // [NUSERS, 128]
    const float* ie   = (const float*)d_in[2];     // [NITEMS, 128]
    const float* Wa   = (const float*)d_in[3];     // [3, 256, 1]
    const float* ba   = (const float*)d_in[4];     // [3, 1]
    const float* Wg   = (const float*)d_in[5];     // [3, 256, 128]
    const float* bg   = (const float*)d_in[6];     // [3, 128]

    const int* src = edge;
    const int* dst = edge + NEDGES;

    float* x   = (float*)d_out;                    // [N,128], evolves in place
    float* agg = (float*)d_ws;                     // [N,128] scratch

    // x = concat(user_emb, item_emb)
    concat_kernel<<<(NNODES * DIM / 4 + 255) / 256, 256, 0, stream>>>(ue, ie, x);

    for (int l = 0; l < NLAYERS; ++l) {
        hipMemsetAsync(agg, 0, (size_t)NNODES * DIM * sizeof(float), stream);
        att_scatter_kernel<<<NEDGES / 4, 256, 0, stream>>>(
            src, dst, x, Wa + (size_t)l * 256, ba + l, agg);
        gemm_relu_kernel<<<NNODES / 32, 256, 0, stream>>>(
            x, agg, Wg + (size_t)l * 256 * DIM, bg + (size_t)l * DIM, x);
    }
}

// Round 2
// 716.210 us; speedup vs baseline: 2.6495x; 2.6495x over previous
//
#include <hip/hip_runtime.h>
#include <cstddef>

#define NUSERS 50000
#define NITEMS 50000
#define NNODES 100000
#define DIM    128
#define NLAYERS 3
#define NEDGES 600000
#define NB_SCAN 391           // ceil(100000/256)

// ---------------------------------------------------------------------------
// concat user/item embeddings into x = d_out  [N,128]
// ---------------------------------------------------------------------------
__global__ void concat_kernel(const float* __restrict__ ue,
                              const float* __restrict__ ie,
                              float* __restrict__ x) {
    int i = blockIdx.x * blockDim.x + threadIdx.x;      // float4 index
    const int uq = NUSERS * DIM / 4;
    const int tq = NNODES * DIM / 4;
    if (i < tq) {
        float4 v = (i < uq) ? ((const float4*)ue)[i]
                            : ((const float4*)ie)[i - uq];
        ((float4*)x)[i] = v;
    }
}

// ---------------------------------------------------------------------------
// CSR build: histogram -> 2-level exclusive scan -> fill
// ---------------------------------------------------------------------------
__global__ void hist_kernel(const int* __restrict__ dst, int* __restrict__ deg) {
    int e = blockIdx.x * blockDim.x + threadIdx.x;
    if (e < NEDGES) atomicAdd(&deg[dst[e]], 1);
}

__global__ void scan_local_kernel(const int* __restrict__ deg,
                                  int* __restrict__ lexcl, int* __restrict__ bsum) {
    const int i = blockIdx.x * 256 + threadIdx.x;
    const int v = (i < NNODES) ? deg[i] : 0;
    const int lane = threadIdx.x & 63, w = threadIdx.x >> 6;
    int s = v;
    #pragma unroll
    for (int o = 1; o < 64; o <<= 1) { int t = __shfl_up(s, o); if (lane >= o) s += t; }
    __shared__ int wsum[4];
    if (lane == 63) wsum[w] = s;
    __syncthreads();
    int add = 0;
    #pragma unroll
    for (int j = 0; j < 3; ++j) if (w > j) add += wsum[j];
    const int incl = s + add;
    if (i < NNODES) lexcl[i] = incl - v;
    if (threadIdx.x == 255) bsum[blockIdx.x] = incl;
}

__global__ void scan_bsum_kernel(int* __restrict__ bsum) {   // in-place exclusive
    const int tid = threadIdx.x;                             // 512 threads
    const int v = (tid < NB_SCAN) ? bsum[tid] : 0;
    const int lane = tid & 63, w = tid >> 6;
    int s = v;
    #pragma unroll
    for (int o = 1; o < 64; o <<= 1) { int t = __shfl_up(s, o); if (lane >= o) s += t; }
    __shared__ int wsum[8];
    if (lane == 63) wsum[w] = s;
    __syncthreads();
    int add = 0;
    #pragma unroll
    for (int j = 0; j < 7; ++j) if (w > j) add += wsum[j];
    if (tid < NB_SCAN) bsum[tid] = s + add - v;
}

__global__ void finalize_rows_kernel(const int* __restrict__ lexcl,
                                     const int* __restrict__ bsum,
                                     int* __restrict__ row_start) {
    const int i = blockIdx.x * 256 + threadIdx.x;
    if (i < NNODES) row_start[i] = lexcl[i] + bsum[blockIdx.x];
    if (i == 0) row_start[NNODES] = NEDGES;
}

__global__ void fill_csr_kernel(const int* __restrict__ src, const int* __restrict__ dst,
                                const int* __restrict__ row_start, int* __restrict__ fill,
                                int* __restrict__ csr_src) {
    int e = blockIdx.x * blockDim.x + threadIdx.x;
    if (e < NEDGES) {
        const int d = dst[e];
        const int pos = row_start[d] + atomicAdd(&fill[d], 1);
        csr_src[pos] = src[e];
    }
}

// ---------------------------------------------------------------------------
// per-node attention dot halves: a_src[n] = x[n]·Wa[0:128], a_dst = x[n]·Wa[128:]
// one wave per node
// ---------------------------------------------------------------------------
__global__ __launch_bounds__(256) void node_dots_kernel(
        const float* __restrict__ x, const float* __restrict__ Wa,
        float* __restrict__ a_src, float* __restrict__ a_dst) {
    const int n = (blockIdx.x * blockDim.x + threadIdx.x) >> 6;
    if (n >= NNODES) return;
    const int lane = threadIdx.x & 63;
    const float2 xv  = *(const float2*)(x + (size_t)n * DIM + lane * 2);
    const float2 wlo = *(const float2*)(Wa + lane * 2);
    const float2 whi = *(const float2*)(Wa + DIM + lane * 2);
    float ps = xv.x * wlo.x + xv.y * wlo.y;
    float pd = xv.x * whi.x + xv.y * whi.y;
    #pragma unroll
    for (int o = 32; o; o >>= 1) { ps += __shfl_xor(ps, o); pd += __shfl_xor(pd, o); }
    if (lane == 0) { a_src[n] = ps; a_dst[n] = pd; }
}

// ---------------------------------------------------------------------------
// pull aggregation: agg[d] = sum over incoming edges of x[s]*sigmoid(a_src[s]+a_dst[d]+ba)
// one wave per dst node; no atomics; writes each agg row exactly once
// ---------------------------------------------------------------------------
__global__ __launch_bounds__(256) void pull_agg_kernel(
        const int* __restrict__ row_start, const int* __restrict__ csr_src,
        const float* __restrict__ x, const float* __restrict__ a_src,
        const float* __restrict__ a_dst, const float* __restrict__ ba,
        float* __restrict__ agg) {
    const int n = (blockIdx.x * blockDim.x + threadIdx.x) >> 6;
    if (n >= NNODES) return;
    const int lane = threadIdx.x & 63;
    const int beg = row_start[n], end = row_start[n + 1];
    const float base = a_dst[n] + ba[0];
    float2 acc = {0.0f, 0.0f};
    for (int i = beg; i < end; ++i) {
        const int s = csr_src[i];
        const float att = 1.0f / (1.0f + __expf(-(a_src[s] + base)));
        const float2 xs = *(const float2*)(x + (size_t)s * DIM + lane * 2);
        acc.x += xs.x * att;
        acc.y += xs.y * att;
    }
    *(float2*)(agg + (size_t)n * DIM + lane * 2) = acc;
}

// ---------------------------------------------------------------------------
// x_new = relu([x || agg] @ Wg + bg)   — in place on x (block owns its rows)
// ---------------------------------------------------------------------------
__global__ __launch_bounds__(256) void gemm_relu_kernel(
        const float* __restrict__ xin, const float* __restrict__ agg,
        const float* __restrict__ Wg,  const float* __restrict__ bg,
        float* __restrict__ xout) {
    __shared__ float in_t[256 * 32];          // [k][row_local]  32 KB

    const int t    = threadIdx.x;
    const int base = blockIdx.x * 32;

    {
        const int rl  = t >> 3;               // 0..31 row_local
        const int kqb = t & 7;                // float4-index base
        const size_t row = (size_t)(base + rl);
        const float4* xr = (const float4*)(xin + row * DIM);
        const float4* ar = (const float4*)(agg + row * DIM);
        #pragma unroll
        for (int j = 0; j < 8; ++j) {
            const int kq = kqb + j * 8;       // 0..63
            const float4 v = (kq < 32) ? xr[kq] : ar[kq - 32];
            const int k0 = kq * 4;
            in_t[(k0 + 0) * 32 + rl] = v.x;
            in_t[(k0 + 1) * 32 + rl] = v.y;
            in_t[(k0 + 2) * 32 + rl] = v.z;
            in_t[(k0 + 3) * 32 + rl] = v.w;
        }
    }
    __syncthreads();

    const int cg = t & 31;                    // cols cg*4..cg*4+3
    const int rg = t >> 5;                    // rows rg*4..rg*4+3

    float4 acc0 = {0,0,0,0}, acc1 = {0,0,0,0}, acc2 = {0,0,0,0}, acc3 = {0,0,0,0};
    const float4* wg4 = (const float4*)Wg;

    #pragma unroll 4
    for (int k = 0; k < 256; ++k) {
        const float4 w = wg4[k * 32 + cg];
        const float4 a = *(const float4*)(&in_t[k * 32 + rg * 4]);
        acc0.x += a.x * w.x; acc0.y += a.x * w.y; acc0.z += a.x * w.z; acc0.w += a.x * w.w;
        acc1.x += a.y * w.x; acc1.y += a.y * w.y; acc1.z += a.y * w.z; acc1.w += a.y * w.w;
        acc2.x += a.z * w.x; acc2.y += a.z * w.y; acc2.z += a.z * w.z; acc2.w += a.z * w.w;
        acc3.x += a.w * w.x; acc3.y += a.w * w.y; acc3.z += a.w * w.z; acc3.w += a.w * w.w;
    }

    const float4 bias = ((const float4*)bg)[cg];
    float4 accs[4] = {acc0, acc1, acc2, acc3};
    #pragma unroll
    for (int r = 0; r < 4; ++r) {
        float4 o;
        o.x = fmaxf(accs[r].x + bias.x, 0.0f);
        o.y = fmaxf(accs[r].y + bias.y, 0.0f);
        o.z = fmaxf(accs[r].z + bias.z, 0.0f);
        o.w = fmaxf(accs[r].w + bias.w, 0.0f);
        ((float4*)(xout + (size_t)(base + rg * 4 + r) * DIM))[cg] = o;
    }
}

// ---------------------------------------------------------------------------
extern "C" void kernel_launch(void* const* d_in, const int* in_sizes, int n_in,
                              void* d_out, int out_size, void* d_ws, size_t ws_size,
                              hipStream_t stream) {
    const int*   edge = (const int*)d_in[0];       // [2, E]
    const float* ue   = (const float*)d_in[1];
    const float* ie   = (const float*)d_in[2];
    const float* Wa   = (const float*)d_in[3];     // [3, 256, 1]
    const float* ba   = (const float*)d_in[4];     // [3, 1]
    const float* Wg   = (const float*)d_in[5];     // [3, 256, 128]
    const float* bg   = (const float*)d_in[6];     // [3, 128]

    const int* src = edge;
    const int* dst = edge + NEDGES;

    float* x = (float*)d_out;                      // [N,128], evolves in place

    // ---- workspace layout (floats/ints, 100096 = 391*256 padded) ----
    float* agg       = (float*)d_ws;               // 12,800,000 f
    float* a_src     = agg + (size_t)NNODES * DIM; // 100,096 f
    float* a_dst     = a_src + 100096;             // 100,096 f
    int*   deg       = (int*)(a_dst + 100096);     // 100,096 i
    int*   fill      = deg + 100096;               // 100,096 i
    int*   lexcl     = fill + 100096;              // 100,096 i
    int*   bsum      = lexcl + 100096;             // 512 i
    int*   row_start = bsum + 512;                 // 100,352 i
    int*   csr_src   = row_start + 100352;         // 600,000 i

    // x = concat(user_emb, item_emb)
    concat_kernel<<<(NNODES * DIM / 4 + 255) / 256, 256, 0, stream>>>(ue, ie, x);

    // ---- build CSR by dst (once per call) ----
    hipMemsetAsync(deg, 0, 2 * 100096 * sizeof(int), stream);   // deg + fill
    hist_kernel<<<(NEDGES + 255) / 256, 256, 0, stream>>>(dst, deg);
    scan_local_kernel<<<NB_SCAN, 256, 0, stream>>>(deg, lexcl, bsum);
    scan_bsum_kernel<<<1, 512, 0, stream>>>(bsum);
    finalize_rows_kernel<<<NB_SCAN, 256, 0, stream>>>(lexcl, bsum, row_start);
    fill_csr_kernel<<<(NEDGES + 255) / 256, 256, 0, stream>>>(src, dst, row_start, fill, csr_src);

    for (int l = 0; l < NLAYERS; ++l) {
        node_dots_kernel<<<(NNODES * 64 + 255) / 256, 256, 0, stream>>>(
            x, Wa + (size_t)l * 256, a_src, a_dst);
        pull_agg_kernel<<<(NNODES * 64 + 255) / 256, 256, 0, stream>>>(
            row_start, csr_src, x, a_src, a_dst, ba + l, agg);
        gemm_relu_kernel<<<NNODES / 32, 256, 0, stream>>>(
            x, agg, Wg + (size_t)l * 256 * DIM, bg + (size_t)l * DIM, x);
    }
}

// Round 3
// 490.909 us; speedup vs baseline: 3.8655x; 1.4589x over previous
//
#include <hip/hip_runtime.h>
#include <cstddef>

#define NUSERS 50000
#define NITEMS 50000
#define NNODES 100000
#define DIM    128
#define NLAYERS 3
#define NEDGES 600000
#define NB_SCAN 391           // ceil(100000/256)
#define NPAD 100096           // 391*256

typedef __attribute__((ext_vector_type(8))) short short8;
typedef __attribute__((ext_vector_type(4))) float f32x4;

__device__ __forceinline__ float bf_lo(unsigned u) { return __uint_as_float(u << 16); }
__device__ __forceinline__ float bf_hi(unsigned u) { return __uint_as_float(u & 0xffff0000u); }
__device__ __forceinline__ unsigned short f2bf(float f) {      // round-nearest-even
    unsigned b = __float_as_uint(f);
    return (unsigned short)((b + 0x7fffu + ((b >> 16) & 1u)) >> 16);
}

// ---------------------------------------------------------------------------
// concat user/item embeddings into bf16 shadow xb [N,128]
// ---------------------------------------------------------------------------
__global__ void concat_kernel(const float* __restrict__ ue,
                              const float* __restrict__ ie,
                              unsigned short* __restrict__ xb) {
    int i = blockIdx.x * blockDim.x + threadIdx.x;      // group of 4 elements
    const int uq = NUSERS * DIM / 4;
    const int tq = NNODES * DIM / 4;
    if (i < tq) {
        float4 v = (i < uq) ? ((const float4*)ue)[i]
                            : ((const float4*)ie)[i - uq];
        ushort4 o = make_ushort4(f2bf(v.x), f2bf(v.y), f2bf(v.z), f2bf(v.w));
        *(ushort4*)(xb + (size_t)i * 4) = o;
    }
}

// Wgt[l][n][k] = Wg[l][k][n]  (bf16 transpose, once per call)
__global__ void wg_conv_kernel(const float* __restrict__ Wg,
                               unsigned short* __restrict__ Wgt) {
    int idx = blockIdx.x * blockDim.x + threadIdx.x;    // 3*256*128
    if (idx < NLAYERS * 256 * DIM) {
        int l = idx / (256 * DIM);
        int r = idx % (256 * DIM);
        int k = r / DIM, n = r % DIM;
        Wgt[(size_t)l * DIM * 256 + (size_t)n * 256 + k] = f2bf(Wg[idx]);
    }
}

// ---------------------------------------------------------------------------
// CSR build: histogram -> 2-level exclusive scan -> fill
// ---------------------------------------------------------------------------
__global__ void hist_kernel(const int* __restrict__ dst, int* __restrict__ deg) {
    int e = blockIdx.x * blockDim.x + threadIdx.x;
    if (e < NEDGES) atomicAdd(&deg[dst[e]], 1);
}

__global__ void scan_local_kernel(const int* __restrict__ deg,
                                  int* __restrict__ row_start, int* __restrict__ bsum) {
    const int i = blockIdx.x * 256 + threadIdx.x;
    const int v = (i < NNODES) ? deg[i] : 0;
    const int lane = threadIdx.x & 63, w = threadIdx.x >> 6;
    int s = v;
    #pragma unroll
    for (int o = 1; o < 64; o <<= 1) { int t = __shfl_up(s, o); if (lane >= o) s += t; }
    __shared__ int wsum[4];
    if (lane == 63) wsum[w] = s;
    __syncthreads();
    int add = 0;
    #pragma unroll
    for (int j = 0; j < 3; ++j) if (w > j) add += wsum[j];
    const int incl = s + add;
    if (i < NNODES) row_start[i] = incl - v;            // local exclusive
    if (threadIdx.x == 255) bsum[blockIdx.x] = incl;
}

__global__ void scan_bsum_kernel(int* __restrict__ bsum) {   // in-place exclusive
    const int tid = threadIdx.x;                             // 512 threads
    const int v = (tid < NB_SCAN) ? bsum[tid] : 0;
    const int lane = tid & 63, w = tid >> 6;
    int s = v;
    #pragma unroll
    for (int o = 1; o < 64; o <<= 1) { int t = __shfl_up(s, o); if (lane >= o) s += t; }
    __shared__ int wsum[8];
    if (lane == 63) wsum[w] = s;
    __syncthreads();
    int add = 0;
    #pragma unroll
    for (int j = 0; j < 7; ++j) if (w > j) add += wsum[j];
    if (tid < NB_SCAN) bsum[tid] = s + add - v;
}

__global__ void finalize_rows_kernel(const int* __restrict__ bsum,
                                     int* __restrict__ row_start) {
    const int i = blockIdx.x * 256 + threadIdx.x;
    if (i < NNODES) row_start[i] += bsum[blockIdx.x];
    if (i == 0) row_start[NNODES] = NEDGES;
}

__global__ void fill_csr_kernel(const int* __restrict__ src, const int* __restrict__ dst,
                                const int* __restrict__ row_start, int* __restrict__ fill,
                                int* __restrict__ csr_src) {
    int e = blockIdx.x * blockDim.x + threadIdx.x;
    if (e < NEDGES) {
        const int d = dst[e];
        const int pos = row_start[d] + atomicAdd(&fill[d], 1);
        csr_src[pos] = src[e];
    }
}

// ---------------------------------------------------------------------------
// per-node attention halves: a_src[n] = x[n]·Wa[0:128]; a_dst[n] = x[n]·Wa[128:]+ba
// ---------------------------------------------------------------------------
__global__ __launch_bounds__(256) void node_dots_kernel(
        const unsigned short* __restrict__ xb, const float* __restrict__ Wa,
        const float* __restrict__ ba,
        float* __restrict__ a_src, float* __restrict__ a_dst) {
    const int n = (blockIdx.x * blockDim.x + threadIdx.x) >> 6;
    if (n >= NNODES) return;
    const int lane = threadIdx.x & 63;
    const unsigned u = *(const unsigned*)(xb + (size_t)n * DIM + lane * 2);
    const float x0 = bf_lo(u), x1 = bf_hi(u);
    const float2 wlo = *(const float2*)(Wa + lane * 2);
    const float2 whi = *(const float2*)(Wa + DIM + lane * 2);
    float ps = x0 * wlo.x + x1 * wlo.y;
    float pd = x0 * whi.x + x1 * whi.y;
    #pragma unroll
    for (int o = 32; o; o >>= 1) { ps += __shfl_xor(ps, o); pd += __shfl_xor(pd, o); }
    if (lane == 0) { a_src[n] = ps; a_dst[n] = pd + ba[0]; }
}

// ---------------------------------------------------------------------------
// pull aggregation: aggb[d] = sum_in x[s]*sigmoid(a_src[s]+a_dst[d]); bf16 in/out
// ---------------------------------------------------------------------------
__global__ __launch_bounds__(256) void pull_agg_kernel(
        const int* __restrict__ row_start, const int* __restrict__ csr_src,
        const unsigned short* __restrict__ xb, const float* __restrict__ a_src,
        const float* __restrict__ a_dst, unsigned short* __restrict__ aggb) {
    const int n = (blockIdx.x * blockDim.x + threadIdx.x) >> 6;
    if (n >= NNODES) return;
    const int lane = threadIdx.x & 63;
    const int beg = row_start[n], end = row_start[n + 1];
    const float base = a_dst[n];
    float ax = 0.0f, ay = 0.0f;
    for (int i = beg; i < end; ++i) {
        const int s = csr_src[i];
        const float att = 1.0f / (1.0f + __expf(-(a_src[s] + base)));
        const unsigned u = *(const unsigned*)(xb + (size_t)s * DIM + lane * 2);
        ax += bf_lo(u) * att;
        ay += bf_hi(u) * att;
    }
    const unsigned out = ((unsigned)f2bf(ay) << 16) | (unsigned)f2bf(ax);
    *(unsigned*)(aggb + (size_t)n * DIM + lane * 2) = out;
}

// ---------------------------------------------------------------------------
// x_new = relu([x || agg] @ Wg + bg) via bf16 MFMA, LDS-free.
// block = 256 thr = 4 waves (2x2), tile 128x128; wave tile 64x64 (4x4 frags).
// A-frags straight from xb/aggb rows; B-frags from L2-resident Wgt[n][k].
// ---------------------------------------------------------------------------
__global__ __launch_bounds__(256) void gemm_mfma_kernel(
        const unsigned short* __restrict__ xb, const unsigned short* __restrict__ aggb,
        const unsigned short* __restrict__ wgt, const float* __restrict__ bg,
        float* __restrict__ xout_f32, unsigned short* __restrict__ xout_bf,
        int write_f32, int write_bf) {
    const int lane  = threadIdx.x & 63;
    const int wid   = threadIdx.x >> 6;
    const int waveM = wid >> 1, waveN = wid & 1;
    const int mbase = blockIdx.x * 128 + waveM * 64;
    const int nbase = waveN * 64;
    const int l16   = lane & 15;
    const int kb    = (lane >> 4) * 8;

    f32x4 acc[4][4] = {};

    int rowA[4];
    #pragma unroll
    for (int mf = 0; mf < 4; ++mf) {
        int r = mbase + mf * 16 + l16;
        rowA[mf] = (r < NNODES) ? r : (NNODES - 1);
    }
    const unsigned short* brow[4];
    #pragma unroll
    for (int nf = 0; nf < 4; ++nf)
        brow[nf] = wgt + (size_t)(nbase + nf * 16 + l16) * 256 + kb;

    #pragma unroll
    for (int ks = 0; ks < 8; ++ks) {
        const unsigned short* ab = (ks < 4) ? xb : aggb;
        const int ko = (ks & 3) * 32 + kb;
        short8 a[4], b[4];
        #pragma unroll
        for (int mf = 0; mf < 4; ++mf)
            a[mf] = *(const short8*)(ab + (size_t)rowA[mf] * DIM + ko);
        #pragma unroll
        for (int nf = 0; nf < 4; ++nf)
            b[nf] = *(const short8*)(brow[nf] + ks * 32);
        #pragma unroll
        for (int mf = 0; mf < 4; ++mf)
            #pragma unroll
            for (int nf = 0; nf < 4; ++nf)
                acc[mf][nf] = __builtin_amdgcn_mfma_f32_16x16x32_bf16(
                    a[mf], b[nf], acc[mf][nf], 0, 0, 0);
    }

    // epilogue: bias + relu; C/D map: col = lane&15, row = (lane>>4)*4 + reg
    const int rsub = (lane >> 4) * 4;
    #pragma unroll
    for (int nf = 0; nf < 4; ++nf) {
        const int col = nbase + nf * 16 + l16;
        const float bias = bg[col];
        #pragma unroll
        for (int mf = 0; mf < 4; ++mf) {
            #pragma unroll
            for (int j = 0; j < 4; ++j) {
                const int row = mbase + mf * 16 + rsub + j;
                if (row >= NNODES) continue;
                float v = fmaxf(acc[mf][nf][j] + bias, 0.0f);
                if (write_f32) xout_f32[(size_t)row * DIM + col] = v;
                if (write_bf)  xout_bf [(size_t)row * DIM + col] = f2bf(v);
            }
        }
    }
}

// ---------------------------------------------------------------------------
extern "C" void kernel_launch(void* const* d_in, const int* in_sizes, int n_in,
                              void* d_out, int out_size, void* d_ws, size_t ws_size,
                              hipStream_t stream) {
    const int*   edge = (const int*)d_in[0];       // [2, E]
    const float* ue   = (const float*)d_in[1];
    const float* ie   = (const float*)d_in[2];
    const float* Wa   = (const float*)d_in[3];     // [3, 256, 1]
    const float* ba   = (const float*)d_in[4];     // [3, 1]
    const float* Wg   = (const float*)d_in[5];     // [3, 256, 128]
    const float* bg   = (const float*)d_in[6];     // [3, 128]

    const int* src = edge;
    const int* dst = edge + NEDGES;

    float* x = (float*)d_out;                      // final f32 output

    // ---- workspace layout ----
    unsigned short* xb   = (unsigned short*)d_ws;            // NPAD*128 bf16
    unsigned short* aggb = xb + (size_t)NPAD * DIM;          // NPAD*128 bf16
    unsigned short* wgt  = aggb + (size_t)NPAD * DIM;        // 3*128*256 bf16
    float* a_src     = (float*)(wgt + NLAYERS * DIM * 256);  // NPAD f
    float* a_dst     = a_src + NPAD;                         // NPAD f
    int*   deg       = (int*)(a_dst + NPAD);                 // NPAD i (also 'fill')
    int*   bsum      = deg + NPAD;                           // 512 i
    int*   row_start = bsum + 512;                           // NPAD+256 i
    int*   csr_src   = row_start + NPAD + 256;               // NEDGES i

    concat_kernel<<<(NNODES * DIM / 4 + 255) / 256, 256, 0, stream>>>(ue, ie, xb);
    wg_conv_kernel<<<(NLAYERS * 256 * DIM + 255) / 256, 256, 0, stream>>>(Wg, wgt);

    // ---- build CSR by dst (once per call) ----
    hipMemsetAsync(deg, 0, NPAD * sizeof(int), stream);
    hist_kernel<<<(NEDGES + 255) / 256, 256, 0, stream>>>(dst, deg);
    scan_local_kernel<<<NB_SCAN, 256, 0, stream>>>(deg, row_start, bsum);
    scan_bsum_kernel<<<1, 512, 0, stream>>>(bsum);
    finalize_rows_kernel<<<NB_SCAN, 256, 0, stream>>>(bsum, row_start);
    hipMemsetAsync(deg, 0, NPAD * sizeof(int), stream);      // reuse as 'fill'
    fill_csr_kernel<<<(NEDGES + 255) / 256, 256, 0, stream>>>(src, dst, row_start, deg, csr_src);

    const int gemm_blocks = (NNODES + 127) / 128;
    for (int l = 0; l < NLAYERS; ++l) {
        node_dots_kernel<<<(NNODES * 64 + 255) / 256, 256, 0, stream>>>(
            xb, Wa + (size_t)l * 256, ba + l, a_src, a_dst);
        pull_agg_kernel<<<(NNODES * 64 + 255) / 256, 256, 0, stream>>>(
            row_start, csr_src, xb, a_src, a_dst, aggb);
        const int last = (l == NLAYERS - 1);
        gemm_mfma_kernel<<<gemm_blocks, 256, 0, stream>>>(
            xb, aggb, wgt + (size_t)l * DIM * 256, bg + (size_t)l * DIM,
            x, xb, last ? 1 : 0, last ? 0 : 1);
    }
}

// Round 4
// 442.051 us; speedup vs baseline: 4.2927x; 1.1105x over previous
//
#include <hip/hip_runtime.h>
#include <cstddef>

#define NUSERS 50000
#define NITEMS 50000
#define NNODES 100000
#define DIM    128
#define NLAYERS 3
#define NEDGES 600000
#define NB_SCAN 391           // ceil(100000/256)
#define NPAD 100096           // 391*256

typedef __attribute__((ext_vector_type(8))) short short8;
typedef __attribute__((ext_vector_type(4))) float f32x4;

__device__ __forceinline__ float bf_lo(unsigned u) { return __uint_as_float(u << 16); }
__device__ __forceinline__ float bf_hi(unsigned u) { return __uint_as_float(u & 0xffff0000u); }
__device__ __forceinline__ unsigned short f2bf(float f) {      // round-nearest-even
    unsigned b = __float_as_uint(f);
    return (unsigned short)((b + 0x7fffu + ((b >> 16) & 1u)) >> 16);
}

// ---------------------------------------------------------------------------
// concat user/item embeddings into bf16 shadow xb [N,128]
// ---------------------------------------------------------------------------
__global__ void concat_kernel(const float* __restrict__ ue,
                              const float* __restrict__ ie,
                              unsigned short* __restrict__ xb) {
    int i = blockIdx.x * blockDim.x + threadIdx.x;      // group of 4 elements
    const int uq = NUSERS * DIM / 4;
    const int tq = NNODES * DIM / 4;
    if (i < tq) {
        float4 v = (i < uq) ? ((const float4*)ue)[i]
                            : ((const float4*)ie)[i - uq];
        ushort4 o = make_ushort4(f2bf(v.x), f2bf(v.y), f2bf(v.z), f2bf(v.w));
        *(ushort4*)(xb + (size_t)i * 4) = o;
    }
}

// Wgt[l][n][k] = Wg[l][k][n]  (bf16 transpose, once per call)
__global__ void wg_conv_kernel(const float* __restrict__ Wg,
                               unsigned short* __restrict__ Wgt) {
    int idx = blockIdx.x * blockDim.x + threadIdx.x;    // 3*256*128
    if (idx < NLAYERS * 256 * DIM) {
        int l = idx / (256 * DIM);
        int r = idx % (256 * DIM);
        int k = r / DIM, n = r % DIM;
        Wgt[(size_t)l * DIM * 256 + (size_t)n * 256 + k] = f2bf(Wg[idx]);
    }
}

// ---------------------------------------------------------------------------
// CSR build: histogram -> 2-level exclusive scan -> fill
// ---------------------------------------------------------------------------
__global__ void hist_kernel(const int* __restrict__ dst, int* __restrict__ deg) {
    int e = blockIdx.x * blockDim.x + threadIdx.x;
    if (e < NEDGES) atomicAdd(&deg[dst[e]], 1);
}

__global__ void scan_local_kernel(const int* __restrict__ deg,
                                  int* __restrict__ row_start, int* __restrict__ bsum) {
    const int i = blockIdx.x * 256 + threadIdx.x;
    const int v = (i < NNODES) ? deg[i] : 0;
    const int lane = threadIdx.x & 63, w = threadIdx.x >> 6;
    int s = v;
    #pragma unroll
    for (int o = 1; o < 64; o <<= 1) { int t = __shfl_up(s, o); if (lane >= o) s += t; }
    __shared__ int wsum[4];
    if (lane == 63) wsum[w] = s;
    __syncthreads();
    int add = 0;
    #pragma unroll
    for (int j = 0; j < 3; ++j) if (w > j) add += wsum[j];
    const int incl = s + add;
    if (i < NNODES) row_start[i] = incl - v;            // local exclusive
    if (threadIdx.x == 255) bsum[blockIdx.x] = incl;
}

__global__ void scan_bsum_kernel(int* __restrict__ bsum) {   // in-place exclusive
    const int tid = threadIdx.x;                             // 512 threads
    const int v = (tid < NB_SCAN) ? bsum[tid] : 0;
    const int lane = tid & 63, w = tid >> 6;
    int s = v;
    #pragma unroll
    for (int o = 1; o < 64; o <<= 1) { int t = __shfl_up(s, o); if (lane >= o) s += t; }
    __shared__ int wsum[8];
    if (lane == 63) wsum[w] = s;
    __syncthreads();
    int add = 0;
    #pragma unroll
    for (int j = 0; j < 7; ++j) if (w > j) add += wsum[j];
    if (tid < NB_SCAN) bsum[tid] = s + add - v;
}

__global__ void finalize_rows_kernel(const int* __restrict__ bsum,
                                     int* __restrict__ row_start) {
    const int i = blockIdx.x * 256 + threadIdx.x;
    if (i < NNODES) row_start[i] += bsum[blockIdx.x];
    if (i == 0) row_start[NNODES] = NEDGES;
}

__global__ void fill_csr_kernel(const int* __restrict__ src, const int* __restrict__ dst,
                                const int* __restrict__ row_start, int* __restrict__ fill,
                                int* __restrict__ csr_src, int* __restrict__ csr_dst) {
    int e = blockIdx.x * blockDim.x + threadIdx.x;
    if (e < NEDGES) {
        const int d = dst[e];
        const int pos = row_start[d] + atomicAdd(&fill[d], 1);
        csr_src[pos] = src[e];
        csr_dst[pos] = d;
    }
}

// ---------------------------------------------------------------------------
// per-node attention halves: a_src[n] = x[n]·Wa[0:128]; a_dst[n] = x[n]·Wa[128:]+ba
// ---------------------------------------------------------------------------
__global__ __launch_bounds__(256) void node_dots_kernel(
        const unsigned short* __restrict__ xb, const float* __restrict__ Wa,
        const float* __restrict__ ba,
        float* __restrict__ a_src, float* __restrict__ a_dst) {
    const int n = (blockIdx.x * blockDim.x + threadIdx.x) >> 6;
    if (n >= NNODES) return;
    const int lane = threadIdx.x & 63;
    const unsigned u = *(const unsigned*)(xb + (size_t)n * DIM + lane * 2);
    const float x0 = bf_lo(u), x1 = bf_hi(u);
    const float2 wlo = *(const float2*)(Wa + lane * 2);
    const float2 whi = *(const float2*)(Wa + DIM + lane * 2);
    float ps = x0 * wlo.x + x1 * wlo.y;
    float pd = x0 * whi.x + x1 * whi.y;
    #pragma unroll
    for (int o = 32; o; o >>= 1) { ps += __shfl_xor(ps, o); pd += __shfl_xor(pd, o); }
    if (lane == 0) { a_src[n] = ps; a_dst[n] = pd + ba[0]; }
}

// ---------------------------------------------------------------------------
// per-edge attention (lane-parallel): att[i] = sigmoid(a_src[s_i] + a_dst[d_i])
// ---------------------------------------------------------------------------
__global__ __launch_bounds__(256) void edge_att_kernel(
        const int* __restrict__ csr_src, const int* __restrict__ csr_dst,
        const float* __restrict__ a_src, const float* __restrict__ a_dst,
        float* __restrict__ att) {
    const int i = blockIdx.x * blockDim.x + threadIdx.x;
    if (i < NEDGES) {
        const float p = a_src[csr_src[i]] + a_dst[csr_dst[i]];
        att[i] = 1.0f / (1.0f + __expf(-p));
    }
}

// ---------------------------------------------------------------------------
// pull aggregation: aggb[d] = sum_in x[s]*att ; pure gather+FMA, 2x unrolled
// ---------------------------------------------------------------------------
__global__ __launch_bounds__(256) void pull_agg_kernel(
        const int* __restrict__ row_start, const int* __restrict__ csr_src,
        const float* __restrict__ att, const unsigned short* __restrict__ xb,
        unsigned short* __restrict__ aggb) {
    const int n = (blockIdx.x * blockDim.x + threadIdx.x) >> 6;
    if (n >= NNODES) return;
    const int lane = threadIdx.x & 63;
    const int beg = row_start[n], end = row_start[n + 1];
    float ax = 0.0f, ay = 0.0f;
    int i = beg;
    for (; i + 1 < end; i += 2) {
        const int s0 = csr_src[i];
        const int s1 = csr_src[i + 1];
        const float w0 = att[i];
        const float w1 = att[i + 1];
        const unsigned u0 = *(const unsigned*)(xb + (size_t)s0 * DIM + lane * 2);
        const unsigned u1 = *(const unsigned*)(xb + (size_t)s1 * DIM + lane * 2);
        ax += bf_lo(u0) * w0;
        ay += bf_hi(u0) * w0;
        ax += bf_lo(u1) * w1;
        ay += bf_hi(u1) * w1;
    }
    if (i < end) {
        const int s = csr_src[i];
        const float w = att[i];
        const unsigned u = *(const unsigned*)(xb + (size_t)s * DIM + lane * 2);
        ax += bf_lo(u) * w;
        ay += bf_hi(u) * w;
    }
    const unsigned out = ((unsigned)f2bf(ay) << 16) | (unsigned)f2bf(ax);
    *(unsigned*)(aggb + (size_t)n * DIM + lane * 2) = out;
}

// ---------------------------------------------------------------------------
// x_new = relu([x || agg] @ Wg + bg) via bf16 MFMA, LDS-free.
// ---------------------------------------------------------------------------
__global__ __launch_bounds__(256) void gemm_mfma_kernel(
        const unsigned short* __restrict__ xb, const unsigned short* __restrict__ aggb,
        const unsigned short* __restrict__ wgt, const float* __restrict__ bg,
        float* __restrict__ xout_f32, unsigned short* __restrict__ xout_bf,
        int write_f32, int write_bf) {
    const int lane  = threadIdx.x & 63;
    const int wid   = threadIdx.x >> 6;
    const int waveM = wid >> 1, waveN = wid & 1;
    const int mbase = blockIdx.x * 128 + waveM * 64;
    const int nbase = waveN * 64;
    const int l16   = lane & 15;
    const int kb    = (lane >> 4) * 8;

    f32x4 acc[4][4] = {};

    int rowA[4];
    #pragma unroll
    for (int mf = 0; mf < 4; ++mf) {
        int r = mbase + mf * 16 + l16;
        rowA[mf] = (r < NNODES) ? r : (NNODES - 1);
    }
    const unsigned short* brow[4];
    #pragma unroll
    for (int nf = 0; nf < 4; ++nf)
        brow[nf] = wgt + (size_t)(nbase + nf * 16 + l16) * 256 + kb;

    #pragma unroll
    for (int ks = 0; ks < 8; ++ks) {
        const unsigned short* ab = (ks < 4) ? xb : aggb;
        const int ko = (ks & 3) * 32 + kb;
        short8 a[4], b[4];
        #pragma unroll
        for (int mf = 0; mf < 4; ++mf)
            a[mf] = *(const short8*)(ab + (size_t)rowA[mf] * DIM + ko);
        #pragma unroll
        for (int nf = 0; nf < 4; ++nf)
            b[nf] = *(const short8*)(brow[nf] + ks * 32);
        #pragma unroll
        for (int mf = 0; mf < 4; ++mf)
            #pragma unroll
            for (int nf = 0; nf < 4; ++nf)
                acc[mf][nf] = __builtin_amdgcn_mfma_f32_16x16x32_bf16(
                    a[mf], b[nf], acc[mf][nf], 0, 0, 0);
    }

    // epilogue: bias + relu; C/D map: col = lane&15, row = (lane>>4)*4 + reg
    const int rsub = (lane >> 4) * 4;
    #pragma unroll
    for (int nf = 0; nf < 4; ++nf) {
        const int col = nbase + nf * 16 + l16;
        const float bias = bg[col];
        #pragma unroll
        for (int mf = 0; mf < 4; ++mf) {
            #pragma unroll
            for (int j = 0; j < 4; ++j) {
                const int row = mbase + mf * 16 + rsub + j;
                if (row >= NNODES) continue;
                float v = fmaxf(acc[mf][nf][j] + bias, 0.0f);
                if (write_f32) xout_f32[(size_t)row * DIM + col] = v;
                if (write_bf)  xout_bf [(size_t)row * DIM + col] = f2bf(v);
            }
        }
    }
}

// ---------------------------------------------------------------------------
extern "C" void kernel_launch(void* const* d_in, const int* in_sizes, int n_in,
                              void* d_out, int out_size, void* d_ws, size_t ws_size,
                              hipStream_t stream) {
    const int*   edge = (const int*)d_in[0];       // [2, E]
    const float* ue   = (const float*)d_in[1];
    const float* ie   = (const float*)d_in[2];
    const float* Wa   = (const float*)d_in[3];     // [3, 256, 1]
    const float* ba   = (const float*)d_in[4];     // [3, 1]
    const float* Wg   = (const float*)d_in[5];     // [3, 256, 128]
    const float* bg   = (const float*)d_in[6];     // [3, 128]

    const int* src = edge;
    const int* dst = edge + NEDGES;

    float* x = (float*)d_out;                      // final f32 output

    // ---- workspace layout ----
    unsigned short* xb   = (unsigned short*)d_ws;            // NPAD*128 bf16
    unsigned short* aggb = xb + (size_t)NPAD * DIM;          // NPAD*128 bf16
    unsigned short* wgt  = aggb + (size_t)NPAD * DIM;        // 3*128*256 bf16
    float* a_src     = (float*)(wgt + NLAYERS * DIM * 256);  // NPAD f
    float* a_dst     = a_src + NPAD;                         // NPAD f
    int*   deg       = (int*)(a_dst + NPAD);                 // NPAD i (also 'fill')
    int*   bsum      = deg + NPAD;                           // 512 i
    int*   row_start = bsum + 512;                           // NPAD+256 i
    int*   csr_src   = row_start + NPAD + 256;               // NEDGES i
    int*   csr_dst   = csr_src + NEDGES;                     // NEDGES i
    float* att       = (float*)(csr_dst + NEDGES);           // NEDGES f

    concat_kernel<<<(NNODES * DIM / 4 + 255) / 256, 256, 0, stream>>>(ue, ie, xb);
    wg_conv_kernel<<<(NLAYERS * 256 * DIM + 255) / 256, 256, 0, stream>>>(Wg, wgt);

    // ---- build CSR by dst (once per call) ----
    hipMemsetAsync(deg, 0, NPAD * sizeof(int), stream);
    hist_kernel<<<(NEDGES + 255) / 256, 256, 0, stream>>>(dst, deg);
    scan_local_kernel<<<NB_SCAN, 256, 0, stream>>>(deg, row_start, bsum);
    scan_bsum_kernel<<<1, 512, 0, stream>>>(bsum);
    finalize_rows_kernel<<<NB_SCAN, 256, 0, stream>>>(bsum, row_start);
    hipMemsetAsync(deg, 0, NPAD * sizeof(int), stream);      // reuse as 'fill'
    fill_csr_kernel<<<(NEDGES + 255) / 256, 256, 0, stream>>>(
        src, dst, row_start, deg, csr_src, csr_dst);

    const int gemm_blocks = (NNODES + 127) / 128;
    for (int l = 0; l < NLAYERS; ++l) {
        node_dots_kernel<<<(NNODES * 64 + 255) / 256, 256, 0, stream>>>(
            xb, Wa + (size_t)l * 256, ba + l, a_src, a_dst);
        edge_att_kernel<<<(NEDGES + 255) / 256, 256, 0, stream>>>(
            csr_src, csr_dst, a_src, a_dst, att);
        pull_agg_kernel<<<(NNODES * 64 + 255) / 256, 256, 0, stream>>>(
            row_start, csr_src, att, xb, aggb);
        const int last = (l == NLAYERS - 1);
        gemm_mfma_kernel<<<gemm_blocks, 256, 0, stream>>>(
            xb, aggb, wgt + (size_t)l * DIM * 256, bg + (size_t)l * DIM,
            x, xb, last ? 1 : 0, last ? 0 : 1);
    }
}

// Round 5
// 357.198 us; speedup vs baseline: 5.3124x; 1.2376x over previous
//
#include <hip/hip_runtime.h>
#include <cstddef>
#include <cstdint>

#define NUSERS 50000
#define NITEMS 50000
#define NNODES 100000
#define DIM    128
#define NLAYERS 3
#define NEDGES 600000
#define NB_SCAN 391           // ceil(100000/256)
#define NPAD 100096           // 391*256  (gives >=96 rows of slack past NNODES)

typedef __attribute__((ext_vector_type(8))) short short8;
typedef __attribute__((ext_vector_type(4))) float f32x4;

__device__ __forceinline__ float bf_lo(unsigned u) { return __uint_as_float(u << 16); }
__device__ __forceinline__ float bf_hi(unsigned u) { return __uint_as_float(u & 0xffff0000u); }
__device__ __forceinline__ unsigned short f2bf(float f) {      // round-nearest-even
    unsigned b = __float_as_uint(f);
    return (unsigned short)((b + 0x7fffu + ((b >> 16) & 1u)) >> 16);
}

// async global->LDS 16B per lane; dst must be wave-uniform base (HW adds lane*16)
__device__ __forceinline__ void async16(const void* g, void* l) {
    __builtin_amdgcn_global_load_lds(
        (const __attribute__((address_space(1))) unsigned int*)(uintptr_t)g,
        (__attribute__((address_space(3))) unsigned int*)(unsigned int)(uintptr_t)l,
        16, 0, 0);
}

// ---------------------------------------------------------------------------
// concat user/item embeddings into bf16 shadow xb [N,128]
// ---------------------------------------------------------------------------
__global__ void concat_kernel(const float* __restrict__ ue,
                              const float* __restrict__ ie,
                              unsigned short* __restrict__ xb) {
    int i = blockIdx.x * blockDim.x + threadIdx.x;      // group of 4 elements
    const int uq = NUSERS * DIM / 4;
    const int tq = NNODES * DIM / 4;
    if (i < tq) {
        float4 v = (i < uq) ? ((const float4*)ue)[i]
                            : ((const float4*)ie)[i - uq];
        ushort4 o = make_ushort4(f2bf(v.x), f2bf(v.y), f2bf(v.z), f2bf(v.w));
        *(ushort4*)(xb + (size_t)i * 4) = o;
    }
}

// ---------------------------------------------------------------------------
// Bf[l][nb][ks][nf][lane][8] = Wg[l][k][col] in MFMA B-fragment order:
//   col = nb*64 + nf*16 + (lane&15),  k = ks*32 + (lane>>4)*8 + j
// ---------------------------------------------------------------------------
__global__ void wg_conv_kernel(const float* __restrict__ Wg,
                               unsigned short* __restrict__ Bf) {
    const int tid = blockIdx.x * blockDim.x + threadIdx.x;   // one per 8 elems
    if (tid >= NLAYERS * 4096) return;
    const int l    = tid >> 12;
    const int slot = tid & 4095;
    const int lane = slot & 63;
    const int t2   = slot >> 6;
    const int nf   = t2 & 3;
    const int t3   = t2 >> 2;
    const int ks   = t3 & 7;
    const int nb   = t3 >> 3;
    const int col  = nb * 64 + nf * 16 + (lane & 15);
    const int k0   = ks * 32 + (lane >> 4) * 8;
    const float* wsrc = Wg + (size_t)l * 256 * DIM;
    unsigned short o[8];
    #pragma unroll
    for (int j = 0; j < 8; ++j) o[j] = f2bf(wsrc[(size_t)(k0 + j) * DIM + col]);
    *(short8*)(Bf + (size_t)tid * 8) = *(short8*)o;
}

// ---------------------------------------------------------------------------
// CSR build: histogram -> 2-level exclusive scan -> fill
// ---------------------------------------------------------------------------
__global__ void hist_kernel(const int* __restrict__ dst, int* __restrict__ deg) {
    int e = blockIdx.x * blockDim.x + threadIdx.x;
    if (e < NEDGES) atomicAdd(&deg[dst[e]], 1);
}

__global__ void scan_local_kernel(const int* __restrict__ deg,
                                  int* __restrict__ row_start, int* __restrict__ bsum) {
    const int i = blockIdx.x * 256 + threadIdx.x;
    const int v = (i < NNODES) ? deg[i] : 0;
    const int lane = threadIdx.x & 63, w = threadIdx.x >> 6;
    int s = v;
    #pragma unroll
    for (int o = 1; o < 64; o <<= 1) { int t = __shfl_up(s, o); if (lane >= o) s += t; }
    __shared__ int wsum[4];
    if (lane == 63) wsum[w] = s;
    __syncthreads();
    int add = 0;
    #pragma unroll
    for (int j = 0; j < 3; ++j) if (w > j) add += wsum[j];
    const int incl = s + add;
    if (i < NNODES) row_start[i] = incl - v;            // local exclusive
    if (threadIdx.x == 255) bsum[blockIdx.x] = incl;
}

__global__ void scan_bsum_kernel(int* __restrict__ bsum) {   // in-place exclusive
    const int tid = threadIdx.x;                             // 512 threads
    const int v = (tid < NB_SCAN) ? bsum[tid] : 0;
    const int lane = tid & 63, w = tid >> 6;
    int s = v;
    #pragma unroll
    for (int o = 1; o < 64; o <<= 1) { int t = __shfl_up(s, o); if (lane >= o) s += t; }
    __shared__ int wsum[8];
    if (lane == 63) wsum[w] = s;
    __syncthreads();
    int add = 0;
    #pragma unroll
    for (int j = 0; j < 7; ++j) if (w > j) add += wsum[j];
    if (tid < NB_SCAN) bsum[tid] = s + add - v;
}

__global__ void finalize_rows_kernel(const int* __restrict__ bsum,
                                     int* __restrict__ row_start) {
    const int i = blockIdx.x * 256 + threadIdx.x;
    if (i < NNODES) row_start[i] += bsum[blockIdx.x];
    if (i == 0) row_start[NNODES] = NEDGES;
}

__global__ void fill_csr_kernel(const int* __restrict__ src, const int* __restrict__ dst,
                                const int* __restrict__ row_start, int* __restrict__ fill,
                                int* __restrict__ csr_src, int* __restrict__ csr_dst) {
    int e = blockIdx.x * blockDim.x + threadIdx.x;
    if (e < NEDGES) {
        const int d = dst[e];
        const int pos = row_start[d] + atomicAdd(&fill[d], 1);
        csr_src[pos] = src[e];
        csr_dst[pos] = d;
    }
}

// ---------------------------------------------------------------------------
// per-node attention halves: a_src[n] = x[n]·Wa[0:128]; a_dst[n] = x[n]·Wa[128:]+ba
// ---------------------------------------------------------------------------
__global__ __launch_bounds__(256) void node_dots_kernel(
        const unsigned short* __restrict__ xb, const float* __restrict__ Wa,
        const float* __restrict__ ba,
        float* __restrict__ a_src, float* __restrict__ a_dst) {
    const int n = (blockIdx.x * blockDim.x + threadIdx.x) >> 6;
    if (n >= NNODES) return;
    const int lane = threadIdx.x & 63;
    const unsigned u = *(const unsigned*)(xb + (size_t)n * DIM + lane * 2);
    const float x0 = bf_lo(u), x1 = bf_hi(u);
    const float2 wlo = *(const float2*)(Wa + lane * 2);
    const float2 whi = *(const float2*)(Wa + DIM + lane * 2);
    float ps = x0 * wlo.x + x1 * wlo.y;
    float pd = x0 * whi.x + x1 * whi.y;
    #pragma unroll
    for (int o = 32; o; o >>= 1) { ps += __shfl_xor(ps, o); pd += __shfl_xor(pd, o); }
    if (lane == 0) { a_src[n] = ps; a_dst[n] = pd + ba[0]; }
}

// ---------------------------------------------------------------------------
// per-edge attention (lane-parallel): att[i] = sigmoid(a_src[s_i] + a_dst[d_i])
// ---------------------------------------------------------------------------
__global__ __launch_bounds__(256) void edge_att_kernel(
        const int* __restrict__ csr_src, const int* __restrict__ csr_dst,
        const float* __restrict__ a_src, const float* __restrict__ a_dst,
        float* __restrict__ att) {
    const int i = blockIdx.x * blockDim.x + threadIdx.x;
    if (i < NEDGES) {
        const float p = a_src[csr_src[i]] + a_dst[csr_dst[i]];
        att[i] = 1.0f / (1.0f + __expf(-p));
    }
}

// ---------------------------------------------------------------------------
// pull aggregation: aggb[d] = sum_in x[s]*att ; 4-deep gather pipeline
// ---------------------------------------------------------------------------
__global__ __launch_bounds__(256) void pull_agg_kernel(
        const int* __restrict__ row_start, const int* __restrict__ csr_src,
        const float* __restrict__ att, const unsigned short* __restrict__ xb,
        unsigned short* __restrict__ aggb) {
    const int n = (blockIdx.x * blockDim.x + threadIdx.x) >> 6;
    if (n >= NNODES) return;
    const int lane = threadIdx.x & 63;
    const int beg = row_start[n], end = row_start[n + 1];
    float ax = 0.0f, ay = 0.0f;
    int i = beg;
    for (; i + 3 < end; i += 4) {
        const int s0 = csr_src[i],     s1 = csr_src[i + 1];
        const int s2 = csr_src[i + 2], s3 = csr_src[i + 3];
        const float w0 = att[i],     w1 = att[i + 1];
        const float w2 = att[i + 2], w3 = att[i + 3];
        const unsigned u0 = *(const unsigned*)(xb + (size_t)s0 * DIM + lane * 2);
        const unsigned u1 = *(const unsigned*)(xb + (size_t)s1 * DIM + lane * 2);
        const unsigned u2 = *(const unsigned*)(xb + (size_t)s2 * DIM + lane * 2);
        const unsigned u3 = *(const unsigned*)(xb + (size_t)s3 * DIM + lane * 2);
        ax += bf_lo(u0) * w0 + bf_lo(u1) * w1 + bf_lo(u2) * w2 + bf_lo(u3) * w3;
        ay += bf_hi(u0) * w0 + bf_hi(u1) * w1 + bf_hi(u2) * w2 + bf_hi(u3) * w3;
    }
    for (; i < end; ++i) {
        const int s = csr_src[i];
        const float w = att[i];
        const unsigned u = *(const unsigned*)(xb + (size_t)s * DIM + lane * 2);
        ax += bf_lo(u) * w;
        ay += bf_hi(u) * w;
    }
    const unsigned out = ((unsigned)f2bf(ay) << 16) | (unsigned)f2bf(ax);
    *(unsigned*)(aggb + (size_t)n * DIM + lane * 2) = out;
}

// ---------------------------------------------------------------------------
// x_new = relu([x || agg] @ Wg + bg) via bf16 MFMA.
// 128x128 tile, 4 waves (2x2), async global_load_lds A-staging into 64KB LDS
// (half0 = xb k0..127, half1 = aggb k128..255), XOR chunk swizzle (row&7) via
// pre-swizzled source. B from fragment-ordered Bf, reg-double-buffered.
// ---------------------------------------------------------------------------
__global__ __launch_bounds__(256) void gemm_mfma_kernel(
        const unsigned short* __restrict__ xb, const unsigned short* __restrict__ aggb,
        const unsigned short* __restrict__ bfr, const float* __restrict__ bg,
        float* __restrict__ xout_f32, unsigned short* __restrict__ xout_bf,
        int write_f32, int write_bf) {
    __shared__ unsigned short At[2][128 * 128];     // 64 KB

    const int tid  = threadIdx.x;
    const int lane = tid & 63;
    const int wid  = tid >> 6;
    const int mbase = blockIdx.x * 128;

    // ---- stage both K-halves: 8 DMA instructions per half per wave ----
    #pragma unroll
    for (int h = 0; h < 2; ++h) {
        const unsigned short* src = h ? aggb : xb;
        #pragma unroll
        for (int i = 0; i < 8; ++i) {
            const int lrow = i * 16 + wid * 4 + (lane >> 4);       // 0..127
            const int c    = (lane & 15) ^ (lrow & 7);             // src chunk
            const unsigned short* g = src + (size_t)(mbase + lrow) * DIM + c * 8;
            async16(g, &At[h][(i * 16 + wid * 4) * 128]);          // uniform base
        }
    }

    const int waveM = wid >> 1, waveN = wid & 1;
    const int l16 = lane & 15, kq = lane >> 4;
    const unsigned short* bfw = bfr + (size_t)(waveN * 8) * 4 * 64 * 8;

    f32x4 acc[4][4] = {};
    short8 bcur[4], bnxt[4];

    // half0 staged (own 8 newest DMAs = half1 still in flight)
    asm volatile("s_waitcnt vmcnt(8)" ::: "memory");
    __builtin_amdgcn_s_barrier();

    #pragma unroll
    for (int nf = 0; nf < 4; ++nf)
        bcur[nf] = *(const short8*)(bfw + ((size_t)(0 * 4 + nf) * 64 + lane) * 8);

    #pragma unroll
    for (int ks = 0; ks < 8; ++ks) {
        if (ks == 4) {                       // half1 staged
            asm volatile("s_waitcnt vmcnt(0)" ::: "memory");
            __builtin_amdgcn_s_barrier();
        }
        if (ks < 7) {
            #pragma unroll
            for (int nf = 0; nf < 4; ++nf)
                bnxt[nf] = *(const short8*)(bfw + ((size_t)((ks + 1) * 4 + nf) * 64 + lane) * 8);
        }
        const int h = ks >> 2, ksl = ks & 3;
        short8 a[4];
        #pragma unroll
        for (int mf = 0; mf < 4; ++mf) {
            const int row   = waveM * 64 + mf * 16 + l16;
            const int chunk = (ksl * 4 + kq) ^ (row & 7);
            a[mf] = *(const short8*)&At[h][row * 128 + chunk * 8];
        }
        #pragma unroll
        for (int mf = 0; mf < 4; ++mf)
            #pragma unroll
            for (int nf = 0; nf < 4; ++nf)
                acc[mf][nf] = __builtin_amdgcn_mfma_f32_16x16x32_bf16(
                    a[mf], bcur[nf], acc[mf][nf], 0, 0, 0);
        if (ks < 7) {
            #pragma unroll
            for (int nf = 0; nf < 4; ++nf) bcur[nf] = bnxt[nf];
        }
    }

    // epilogue: bias + relu; C/D map: col = lane&15, row = kq*4 + reg
    const int rsub = kq * 4;
    #pragma unroll
    for (int nf = 0; nf < 4; ++nf) {
        const int col  = waveN * 64 + nf * 16 + l16;
        const float bias = bg[col];
        #pragma unroll
        for (int mf = 0; mf < 4; ++mf) {
            #pragma unroll
            for (int j = 0; j < 4; ++j) {
                const int row = mbase + waveM * 64 + mf * 16 + rsub + j;
                const float v = fmaxf(acc[mf][nf][j] + bias, 0.0f);
                if (write_f32 && row < NNODES)
                    xout_f32[(size_t)row * DIM + col] = v;
                if (write_bf) {
                    const unsigned short b = f2bf(v);
                    const unsigned pb = (unsigned)(unsigned short)__shfl_xor((int)b, 1);
                    if (!(l16 & 1) && row < NNODES) {
                        const unsigned packed = (unsigned)b | (pb << 16);
                        *(unsigned*)(xout_bf + (size_t)row * DIM + col) = packed;
                    }
                }
            }
        }
    }
}

// ---------------------------------------------------------------------------
extern "C" void kernel_launch(void* const* d_in, const int* in_sizes, int n_in,
                              void* d_out, int out_size, void* d_ws, size_t ws_size,
                              hipStream_t stream) {
    const int*   edge = (const int*)d_in[0];       // [2, E]
    const float* ue   = (const float*)d_in[1];
    const float* ie   = (const float*)d_in[2];
    const float* Wa   = (const float*)d_in[3];     // [3, 256, 1]
    const float* ba   = (const float*)d_in[4];     // [3, 1]
    const float* Wg   = (const float*)d_in[5];     // [3, 256, 128]
    const float* bg   = (const float*)d_in[6];     // [3, 128]

    const int* src = edge;
    const int* dst = edge + NEDGES;

    float* x = (float*)d_out;                      // final f32 output

    // ---- workspace layout ----
    unsigned short* xb   = (unsigned short*)d_ws;            // NPAD*128 bf16
    unsigned short* aggb = xb + (size_t)NPAD * DIM;          // NPAD*128 bf16
    unsigned short* bfr  = aggb + (size_t)NPAD * DIM;        // 3*32768 bf16
    float* a_src     = (float*)(bfr + NLAYERS * 32768);      // NPAD f
    float* a_dst     = a_src + NPAD;                         // NPAD f
    int*   deg       = (int*)(a_dst + NPAD);                 // NPAD i (also 'fill')
    int*   bsum      = deg + NPAD;                           // 512 i
    int*   row_start = bsum + 512;                           // NPAD+256 i
    int*   csr_src   = row_start + NPAD + 256;               // NEDGES i
    int*   csr_dst   = csr_src + NEDGES;                     // NEDGES i
    float* att       = (float*)(csr_dst + NEDGES);           // NEDGES f

    concat_kernel<<<(NNODES * DIM / 4 + 255) / 256, 256, 0, stream>>>(ue, ie, xb);
    wg_conv_kernel<<<(NLAYERS * 4096 + 255) / 256, 256, 0, stream>>>(Wg, bfr);

    // ---- build CSR by dst (once per call) ----
    hipMemsetAsync(deg, 0, NPAD * sizeof(int), stream);
    hist_kernel<<<(NEDGES + 255) / 256, 256, 0, stream>>>(dst, deg);
    scan_local_kernel<<<NB_SCAN, 256, 0, stream>>>(deg, row_start, bsum);
    scan_bsum_kernel<<<1, 512, 0, stream>>>(bsum);
    finalize_rows_kernel<<<NB_SCAN, 256, 0, stream>>>(bsum, row_start);
    hipMemsetAsync(deg, 0, NPAD * sizeof(int), stream);      // reuse as 'fill'
    fill_csr_kernel<<<(NEDGES + 255) / 256, 256, 0, stream>>>(
        src, dst, row_start, deg, csr_src, csr_dst);

    const int gemm_blocks = (NNODES + 127) / 128;            // 782
    for (int l = 0; l < NLAYERS; ++l) {
        node_dots_kernel<<<(NNODES * 64 + 255) / 256, 256, 0, stream>>>(
            xb, Wa + (size_t)l * 256, ba + l, a_src, a_dst);
        edge_att_kernel<<<(NEDGES + 255) / 256, 256, 0, stream>>>(
            csr_src, csr_dst, a_src, a_dst, att);
        pull_agg_kernel<<<(NNODES * 64 + 255) / 256, 256, 0, stream>>>(
            row_start, csr_src, att, xb, aggb);
        const int last = (l == NLAYERS - 1);
        gemm_mfma_kernel<<<gemm_blocks, 256, 0, stream>>>(
            xb, aggb, bfr + (size_t)l * 32768, bg + (size_t)l * DIM,
            x, xb, last ? 1 : 0, last ? 0 : 1);
    }
}

// Round 6
// 304.787 us; speedup vs baseline: 6.2259x; 1.1720x over previous
//
#include <hip/hip_runtime.h>
#include <cstddef>
#include <cstdint>

#define NUSERS 50000
#define NITEMS 50000
#define NNODES 100000
#define DIM    128
#define NLAYERS 3
#define NEDGES 600000
#define NB_SCAN 391           // ceil(100000/256)
#define NPAD 100096           // 391*256  (gives >=96 rows of slack past NNODES)

typedef __attribute__((ext_vector_type(8))) short short8;
typedef __attribute__((ext_vector_type(4))) float f32x4;

__device__ __forceinline__ float bf_lo(unsigned u) { return __uint_as_float(u << 16); }
__device__ __forceinline__ float bf_hi(unsigned u) { return __uint_as_float(u & 0xffff0000u); }
__device__ __forceinline__ unsigned short f2bf(float f) {      // round-nearest-even
    unsigned b = __float_as_uint(f);
    return (unsigned short)((b + 0x7fffu + ((b >> 16) & 1u)) >> 16);
}

// async global->LDS 16B per lane; dst must be wave-uniform base (HW adds lane*16)
__device__ __forceinline__ void async16(const void* g, void* l) {
    __builtin_amdgcn_global_load_lds(
        (const __attribute__((address_space(1))) unsigned int*)(uintptr_t)g,
        (__attribute__((address_space(3))) unsigned int*)(unsigned int)(uintptr_t)l,
        16, 0, 0);
}

// ---------------------------------------------------------------------------
// concat user/item embeddings into bf16 shadow xb [N,128]
// ---------------------------------------------------------------------------
__global__ void concat_kernel(const float* __restrict__ ue,
                              const float* __restrict__ ie,
                              unsigned short* __restrict__ xb) {
    int i = blockIdx.x * blockDim.x + threadIdx.x;      // group of 4 elements
    const int uq = NUSERS * DIM / 4;
    const int tq = NNODES * DIM / 4;
    if (i < tq) {
        float4 v = (i < uq) ? ((const float4*)ue)[i]
                            : ((const float4*)ie)[i - uq];
        ushort4 o = make_ushort4(f2bf(v.x), f2bf(v.y), f2bf(v.z), f2bf(v.w));
        *(ushort4*)(xb + (size_t)i * 4) = o;
    }
}

// ---------------------------------------------------------------------------
// Bf[l][nb][ks][nf][lane][8] = Wg[l][k][col] in MFMA B-fragment order:
//   col = nb*64 + nf*16 + (lane&15),  k = ks*32 + (lane>>4)*8 + j
// ---------------------------------------------------------------------------
__global__ void wg_conv_kernel(const float* __restrict__ Wg,
                               unsigned short* __restrict__ Bf) {
    const int tid = blockIdx.x * blockDim.x + threadIdx.x;   // one per 8 elems
    if (tid >= NLAYERS * 4096) return;
    const int l    = tid >> 12;
    const int slot = tid & 4095;
    const int lane = slot & 63;
    const int t2   = slot >> 6;
    const int nf   = t2 & 3;
    const int t3   = t2 >> 2;
    const int ks   = t3 & 7;
    const int nb   = t3 >> 3;
    const int col  = nb * 64 + nf * 16 + (lane & 15);
    const int k0   = ks * 32 + (lane >> 4) * 8;
    const float* wsrc = Wg + (size_t)l * 256 * DIM;
    unsigned short o[8];
    #pragma unroll
    for (int j = 0; j < 8; ++j) o[j] = f2bf(wsrc[(size_t)(k0 + j) * DIM + col]);
    *(short8*)(Bf + (size_t)tid * 8) = *(short8*)o;
}

// ---------------------------------------------------------------------------
// CSR build: histogram -> 2-level exclusive scan -> fill
// ---------------------------------------------------------------------------
__global__ void hist_kernel(const int* __restrict__ dst, int* __restrict__ deg) {
    int e = blockIdx.x * blockDim.x + threadIdx.x;
    if (e < NEDGES) atomicAdd(&deg[dst[e]], 1);
}

__global__ void scan_local_kernel(const int* __restrict__ deg,
                                  int* __restrict__ row_start, int* __restrict__ bsum) {
    const int i = blockIdx.x * 256 + threadIdx.x;
    const int v = (i < NNODES) ? deg[i] : 0;
    const int lane = threadIdx.x & 63, w = threadIdx.x >> 6;
    int s = v;
    #pragma unroll
    for (int o = 1; o < 64; o <<= 1) { int t = __shfl_up(s, o); if (lane >= o) s += t; }
    __shared__ int wsum[4];
    if (lane == 63) wsum[w] = s;
    __syncthreads();
    int add = 0;
    #pragma unroll
    for (int j = 0; j < 3; ++j) if (w > j) add += wsum[j];
    const int incl = s + add;
    if (i < NNODES) row_start[i] = incl - v;            // local exclusive
    if (threadIdx.x == 255) bsum[blockIdx.x] = incl;
}

__global__ void scan_bsum_kernel(int* __restrict__ bsum) {   // in-place exclusive
    const int tid = threadIdx.x;                             // 512 threads
    const int v = (tid < NB_SCAN) ? bsum[tid] : 0;
    const int lane = tid & 63, w = tid >> 6;
    int s = v;
    #pragma unroll
    for (int o = 1; o < 64; o <<= 1) { int t = __shfl_up(s, o); if (lane >= o) s += t; }
    __shared__ int wsum[8];
    if (lane == 63) wsum[w] = s;
    __syncthreads();
    int add = 0;
    #pragma unroll
    for (int j = 0; j < 7; ++j) if (w > j) add += wsum[j];
    if (tid < NB_SCAN) bsum[tid] = s + add - v;
}

__global__ void finalize_rows_kernel(const int* __restrict__ bsum,
                                     int* __restrict__ row_start) {
    const int i = blockIdx.x * 256 + threadIdx.x;
    if (i < NNODES) row_start[i] += bsum[blockIdx.x];
    if (i == 0) row_start[NNODES] = NEDGES;
}

__global__ void fill_csr_kernel(const int* __restrict__ src, const int* __restrict__ dst,
                                const int* __restrict__ row_start, int* __restrict__ fill,
                                int* __restrict__ csr_src) {
    int e = blockIdx.x * blockDim.x + threadIdx.x;
    if (e < NEDGES) {
        const int d = dst[e];
        const int pos = row_start[d] + atomicAdd(&fill[d], 1);
        csr_src[pos] = src[e];
    }
}

// ---------------------------------------------------------------------------
// per-node attention halves: a_src[n] = x[n]·Wa[0:128]; a_dst[n] = x[n]·Wa[128:]+ba
// ---------------------------------------------------------------------------
__global__ __launch_bounds__(256) void node_dots_kernel(
        const unsigned short* __restrict__ xb, const float* __restrict__ Wa,
        const float* __restrict__ ba,
        float* __restrict__ a_src, float* __restrict__ a_dst) {
    const int n = (blockIdx.x * blockDim.x + threadIdx.x) >> 6;
    if (n >= NNODES) return;
    const int lane = threadIdx.x & 63;
    const unsigned u = *(const unsigned*)(xb + (size_t)n * DIM + lane * 2);
    const float x0 = bf_lo(u), x1 = bf_hi(u);
    const float2 wlo = *(const float2*)(Wa + lane * 2);
    const float2 whi = *(const float2*)(Wa + DIM + lane * 2);
    float ps = x0 * wlo.x + x1 * wlo.y;
    float pd = x0 * whi.x + x1 * whi.y;
    #pragma unroll
    for (int o = 32; o; o >>= 1) { ps += __shfl_xor(ps, o); pd += __shfl_xor(pd, o); }
    if (lane == 0) { a_src[n] = ps; a_dst[n] = pd + ba[0]; }
}

// ---------------------------------------------------------------------------
// pull aggregation, quarter-wave (16 lanes = one node, 16B/lane):
//   per 16-edge chunk: sub-lane computes sigmoid for its edge, then the
//   quarter processes edges 4-at-a-time via __shfl broadcast of (src, att).
// aggb[d] = sum_in x[s]*att; fused attention, no att[] array, no csr_dst.
// ---------------------------------------------------------------------------
__global__ __launch_bounds__(256) void pull_agg_kernel(
        const int* __restrict__ row_start, const int* __restrict__ csr_src,
        const float* __restrict__ a_src, const float* __restrict__ a_dst,
        const unsigned short* __restrict__ xb, unsigned short* __restrict__ aggb) {
    const int n = blockIdx.x * 16 + (threadIdx.x >> 4);
    if (n >= NNODES) return;
    const int lane = threadIdx.x & 63;
    const int sub  = lane & 15;        // position within quarter
    const int qb   = lane & 48;        // quarter base lane
    const int beg = row_start[n], end = row_start[n + 1];
    const float adst = a_dst[n];

    float a0 = 0, a1 = 0, a2 = 0, a3 = 0, a4 = 0, a5 = 0, a6 = 0, a7 = 0;

    for (int base = beg; base < end; base += 16) {
        const int rem = end - base;
        const int cnt = rem < 16 ? rem : 16;
        int   idx_l = 0;
        float att_l = 0.0f;
        if (sub < cnt) {
            idx_l = csr_src[base + sub];
            att_l = 1.0f / (1.0f + __expf(-(a_src[idx_l] + adst)));
        }
        int i = 0;
        for (; i + 3 < cnt; i += 4) {
            const int   s0 = __shfl(idx_l, qb + i);
            const int   s1 = __shfl(idx_l, qb + i + 1);
            const int   s2 = __shfl(idx_l, qb + i + 2);
            const int   s3 = __shfl(idx_l, qb + i + 3);
            const float w0 = __shfl(att_l, qb + i);
            const float w1 = __shfl(att_l, qb + i + 1);
            const float w2 = __shfl(att_l, qb + i + 2);
            const float w3 = __shfl(att_l, qb + i + 3);
            const uint4 u0 = *(const uint4*)(xb + (size_t)s0 * DIM + sub * 8);
            const uint4 u1 = *(const uint4*)(xb + (size_t)s1 * DIM + sub * 8);
            const uint4 u2 = *(const uint4*)(xb + (size_t)s2 * DIM + sub * 8);
            const uint4 u3 = *(const uint4*)(xb + (size_t)s3 * DIM + sub * 8);
            a0 += bf_lo(u0.x) * w0 + bf_lo(u1.x) * w1 + bf_lo(u2.x) * w2 + bf_lo(u3.x) * w3;
            a1 += bf_hi(u0.x) * w0 + bf_hi(u1.x) * w1 + bf_hi(u2.x) * w2 + bf_hi(u3.x) * w3;
            a2 += bf_lo(u0.y) * w0 + bf_lo(u1.y) * w1 + bf_lo(u2.y) * w2 + bf_lo(u3.y) * w3;
            a3 += bf_hi(u0.y) * w0 + bf_hi(u1.y) * w1 + bf_hi(u2.y) * w2 + bf_hi(u3.y) * w3;
            a4 += bf_lo(u0.z) * w0 + bf_lo(u1.z) * w1 + bf_lo(u2.z) * w2 + bf_lo(u3.z) * w3;
            a5 += bf_hi(u0.z) * w0 + bf_hi(u1.z) * w1 + bf_hi(u2.z) * w2 + bf_hi(u3.z) * w3;
            a6 += bf_lo(u0.w) * w0 + bf_lo(u1.w) * w1 + bf_lo(u2.w) * w2 + bf_lo(u3.w) * w3;
            a7 += bf_hi(u0.w) * w0 + bf_hi(u1.w) * w1 + bf_hi(u2.w) * w2 + bf_hi(u3.w) * w3;
        }
        for (; i < cnt; ++i) {
            const int   s = __shfl(idx_l, qb + i);
            const float w = __shfl(att_l, qb + i);
            const uint4 u = *(const uint4*)(xb + (size_t)s * DIM + sub * 8);
            a0 += bf_lo(u.x) * w;  a1 += bf_hi(u.x) * w;
            a2 += bf_lo(u.y) * w;  a3 += bf_hi(u.y) * w;
            a4 += bf_lo(u.z) * w;  a5 += bf_hi(u.z) * w;
            a6 += bf_lo(u.w) * w;  a7 += bf_hi(u.w) * w;
        }
    }

    uint4 o;
    o.x = ((unsigned)f2bf(a1) << 16) | (unsigned)f2bf(a0);
    o.y = ((unsigned)f2bf(a3) << 16) | (unsigned)f2bf(a2);
    o.z = ((unsigned)f2bf(a5) << 16) | (unsigned)f2bf(a4);
    o.w = ((unsigned)f2bf(a7) << 16) | (unsigned)f2bf(a6);
    *(uint4*)(aggb + (size_t)n * DIM + sub * 8) = o;
}

// ---------------------------------------------------------------------------
// x_new = relu([x || agg] @ Wg + bg) via bf16 MFMA.
// 128x128 tile, 4 waves (2x2), async global_load_lds A-staging into 64KB LDS
// (half0 = xb k0..127, half1 = aggb k128..255), XOR chunk swizzle (row&7) via
// pre-swizzled source. B from fragment-ordered Bf, reg-double-buffered.
// ---------------------------------------------------------------------------
__global__ __launch_bounds__(256) void gemm_mfma_kernel(
        const unsigned short* __restrict__ xb, const unsigned short* __restrict__ aggb,
        const unsigned short* __restrict__ bfr, const float* __restrict__ bg,
        float* __restrict__ xout_f32, unsigned short* __restrict__ xout_bf,
        int write_f32, int write_bf) {
    __shared__ unsigned short At[2][128 * 128];     // 64 KB

    const int tid  = threadIdx.x;
    const int lane = tid & 63;
    const int wid  = tid >> 6;
    const int mbase = blockIdx.x * 128;

    // ---- stage both K-halves: 8 DMA instructions per half per wave ----
    #pragma unroll
    for (int h = 0; h < 2; ++h) {
        const unsigned short* src = h ? aggb : xb;
        #pragma unroll
        for (int i = 0; i < 8; ++i) {
            const int lrow = i * 16 + wid * 4 + (lane >> 4);       // 0..127
            const int c    = (lane & 15) ^ (lrow & 7);             // src chunk
            const unsigned short* g = src + (size_t)(mbase + lrow) * DIM + c * 8;
            async16(g, &At[h][(i * 16 + wid * 4) * 128]);          // uniform base
        }
    }

    const int waveM = wid >> 1, waveN = wid & 1;
    const int l16 = lane & 15, kq = lane >> 4;
    const unsigned short* bfw = bfr + (size_t)(waveN * 8) * 4 * 64 * 8;

    f32x4 acc[4][4] = {};
    short8 bcur[4], bnxt[4];

    // half0 staged (own 8 newest DMAs = half1 still in flight)
    asm volatile("s_waitcnt vmcnt(8)" ::: "memory");
    __builtin_amdgcn_s_barrier();

    #pragma unroll
    for (int nf = 0; nf < 4; ++nf)
        bcur[nf] = *(const short8*)(bfw + ((size_t)(0 * 4 + nf) * 64 + lane) * 8);

    #pragma unroll
    for (int ks = 0; ks < 8; ++ks) {
        if (ks == 4) {                       // half1 staged
            asm volatile("s_waitcnt vmcnt(0)" ::: "memory");
            __builtin_amdgcn_s_barrier();
        }
        if (ks < 7) {
            #pragma unroll
            for (int nf = 0; nf < 4; ++nf)
                bnxt[nf] = *(const short8*)(bfw + ((size_t)((ks + 1) * 4 + nf) * 64 + lane) * 8);
        }
        const int h = ks >> 2, ksl = ks & 3;
        short8 a[4];
        #pragma unroll
        for (int mf = 0; mf < 4; ++mf) {
            const int row   = waveM * 64 + mf * 16 + l16;
            const int chunk = (ksl * 4 + kq) ^ (row & 7);
            a[mf] = *(const short8*)&At[h][row * 128 + chunk * 8];
        }
        #pragma unroll
        for (int mf = 0; mf < 4; ++mf)
            #pragma unroll
            for (int nf = 0; nf < 4; ++nf)
                acc[mf][nf] = __builtin_amdgcn_mfma_f32_16x16x32_bf16(
                    a[mf], bcur[nf], acc[mf][nf], 0, 0, 0);
        if (ks < 7) {
            #pragma unroll
            for (int nf = 0; nf < 4; ++nf) bcur[nf] = bnxt[nf];
        }
    }

    // epilogue: bias + relu; C/D map: col = lane&15, row = kq*4 + reg
    const int rsub = kq * 4;
    #pragma unroll
    for (int nf = 0; nf < 4; ++nf) {
        const int col  = waveN * 64 + nf * 16 + l16;
        const float bias = bg[col];
        #pragma unroll
        for (int mf = 0; mf < 4; ++mf) {
            #pragma unroll
            for (int j = 0; j < 4; ++j) {
                const int row = mbase + waveM * 64 + mf * 16 + rsub + j;
                const float v = fmaxf(acc[mf][nf][j] + bias, 0.0f);
                if (write_f32 && row < NNODES)
                    xout_f32[(size_t)row * DIM + col] = v;
                if (write_bf) {
                    const unsigned short b = f2bf(v);
                    const unsigned pb = (unsigned)(unsigned short)__shfl_xor((int)b, 1);
                    if (!(l16 & 1) && row < NNODES) {
                        const unsigned packed = (unsigned)b | (pb << 16);
                        *(unsigned*)(xout_bf + (size_t)row * DIM + col) = packed;
                    }
                }
            }
        }
    }
}

// ---------------------------------------------------------------------------
extern "C" void kernel_launch(void* const* d_in, const int* in_sizes, int n_in,
                              void* d_out, int out_size, void* d_ws, size_t ws_size,
                              hipStream_t stream) {
    const int*   edge = (const int*)d_in[0];       // [2, E]
    const float* ue   = (const float*)d_in[1];
    const float* ie   = (const float*)d_in[2];
    const float* Wa   = (const float*)d_in[3];     // [3, 256, 1]
    const float* ba   = (const float*)d_in[4];     // [3, 1]
    const float* Wg   = (const float*)d_in[5];     // [3, 256, 128]
    const float* bg   = (const float*)d_in[6];     // [3, 128]

    const int* src = edge;
    const int* dst = edge + NEDGES;

    float* x = (float*)d_out;                      // final f32 output

    // ---- workspace layout ----
    unsigned short* xb   = (unsigned short*)d_ws;            // NPAD*128 bf16
    unsigned short* aggb = xb + (size_t)NPAD * DIM;          // NPAD*128 bf16
    unsigned short* bfr  = aggb + (size_t)NPAD * DIM;        // 3*32768 bf16
    float* a_src     = (float*)(bfr + NLAYERS * 32768);      // NPAD f
    float* a_dst     = a_src + NPAD;                         // NPAD f
    int*   deg       = (int*)(a_dst + NPAD);                 // NPAD i (also 'fill')
    int*   bsum      = deg + NPAD;                           // 512 i
    int*   row_start = bsum + 512;                           // NPAD+256 i
    int*   csr_src   = row_start + NPAD + 256;               // NEDGES i

    concat_kernel<<<(NNODES * DIM / 4 + 255) / 256, 256, 0, stream>>>(ue, ie, xb);
    wg_conv_kernel<<<(NLAYERS * 4096 + 255) / 256, 256, 0, stream>>>(Wg, bfr);

    // ---- build CSR by dst (once per call) ----
    hipMemsetAsync(deg, 0, NPAD * sizeof(int), stream);
    hist_kernel<<<(NEDGES + 255) / 256, 256, 0, stream>>>(dst, deg);
    scan_local_kernel<<<NB_SCAN, 256, 0, stream>>>(deg, row_start, bsum);
    scan_bsum_kernel<<<1, 512, 0, stream>>>(bsum);
    finalize_rows_kernel<<<NB_SCAN, 256, 0, stream>>>(bsum, row_start);
    hipMemsetAsync(deg, 0, NPAD * sizeof(int), stream);      // reuse as 'fill'
    fill_csr_kernel<<<(NEDGES + 255) / 256, 256, 0, stream>>>(
        src, dst, row_start, deg, csr_src);

    const int gemm_blocks = (NNODES + 127) / 128;            // 782
    const int pull_blocks = (NNODES + 15) / 16;              // 6250
    for (int l = 0; l < NLAYERS; ++l) {
        node_dots_kernel<<<(NNODES * 64 + 255) / 256, 256, 0, stream>>>(
            xb, Wa + (size_t)l * 256, ba + l, a_src, a_dst);
        pull_agg_kernel<<<pull_blocks, 256, 0, stream>>>(
            row_start, csr_src, a_src, a_dst, xb, aggb);
        const int last = (l == NLAYERS - 1);
        gemm_mfma_kernel<<<gemm_blocks, 256, 0, stream>>>(
            xb, aggb, bfr + (size_t)l * 32768, bg + (size_t)l * DIM,
            x, xb, last ? 1 : 0, last ? 0 : 1);
    }
}

// Round 7
// 285.788 us; speedup vs baseline: 6.6398x; 1.0665x over previous
//
#include <hip/hip_runtime.h>
#include <cstddef>
#include <cstdint>

#define NUSERS 50000
#define NITEMS 50000
#define NNODES 100000
#define DIM    128
#define NLAYERS 3
#define NEDGES 600000
#define NPAD 100096           // 391*256  (>=96 rows of slack past NNODES)

#define EBLK  8192            // edges per binning block
#define NBLK  74              // ceil(600000/8192)
#define NBUCK 782             // ceil(100000/128), bucket = dst>>7

typedef __attribute__((ext_vector_type(8))) short short8;
typedef __attribute__((ext_vector_type(4))) float f32x4;

__device__ __forceinline__ float bf_lo(unsigned u) { return __uint_as_float(u << 16); }
__device__ __forceinline__ float bf_hi(unsigned u) { return __uint_as_float(u & 0xffff0000u); }
__device__ __forceinline__ unsigned short f2bf(float f) {      // round-nearest-even
    unsigned b = __float_as_uint(f);
    return (unsigned short)((b + 0x7fffu + ((b >> 16) & 1u)) >> 16);
}

// async global->LDS 16B per lane; dst must be wave-uniform base (HW adds lane*16)
__device__ __forceinline__ void async16(const void* g, void* l) {
    __builtin_amdgcn_global_load_lds(
        (const __attribute__((address_space(1))) unsigned int*)(uintptr_t)g,
        (__attribute__((address_space(3))) unsigned int*)(unsigned int)(uintptr_t)l,
        16, 0, 0);
}

// ---------------------------------------------------------------------------
// concat user/item embeddings into bf16 shadow xb [N,128]
// ---------------------------------------------------------------------------
__global__ void concat_kernel(const float* __restrict__ ue,
                              const float* __restrict__ ie,
                              unsigned short* __restrict__ xb) {
    int i = blockIdx.x * blockDim.x + threadIdx.x;      // group of 4 elements
    const int uq = NUSERS * DIM / 4;
    const int tq = NNODES * DIM / 4;
    if (i < tq) {
        float4 v = (i < uq) ? ((const float4*)ue)[i]
                            : ((const float4*)ie)[i - uq];
        ushort4 o = make_ushort4(f2bf(v.x), f2bf(v.y), f2bf(v.z), f2bf(v.w));
        *(ushort4*)(xb + (size_t)i * 4) = o;
    }
}

// ---------------------------------------------------------------------------
// Bf[l][nb][ks][nf][lane][8] = Wg[l][k][col] in MFMA B-fragment order
// ---------------------------------------------------------------------------
__global__ void wg_conv_kernel(const float* __restrict__ Wg,
                               unsigned short* __restrict__ Bf) {
    const int tid = blockIdx.x * blockDim.x + threadIdx.x;   // one per 8 elems
    if (tid >= NLAYERS * 4096) return;
    const int l    = tid >> 12;
    const int slot = tid & 4095;
    const int lane = slot & 63;
    const int t2   = slot >> 6;
    const int nf   = t2 & 3;
    const int t3   = t2 >> 2;
    const int ks   = t3 & 7;
    const int nb   = t3 >> 3;
    const int col  = nb * 64 + nf * 16 + (lane & 15);
    const int k0   = ks * 32 + (lane >> 4) * 8;
    const float* wsrc = Wg + (size_t)l * 256 * DIM;
    unsigned short o[8];
    #pragma unroll
    for (int j = 0; j < 8; ++j) o[j] = f2bf(wsrc[(size_t)(k0 + j) * DIM + col]);
    *(short8*)(Bf + (size_t)tid * 8) = *(short8*)o;
}

// ---------------------------------------------------------------------------
// binned CSR build (no device-wide random 4B scatter):
//   P1 bin_count: per-block LDS histogram of dst>>7
//   P2a col_prefix: per-bucket exclusive prefix over blocks (in-place)
//   P2b base_scan: exclusive scan of bucket totals -> bucketbase
//   P3 bin_scatter: pack (dlocal<<17|src) into bucket-major pairs
//   P4 bucket_csr: per-bucket (one block) degree count -> scan ->
//                  row_start (coalesced) + in-window rank placement
// ---------------------------------------------------------------------------
__global__ __launch_bounds__(256) void bin_count_kernel(
        const int* __restrict__ dst, unsigned* __restrict__ counts) {
    __shared__ unsigned hist[NBUCK];
    for (int i = threadIdx.x; i < NBUCK; i += 256) hist[i] = 0;
    __syncthreads();
    const int base = blockIdx.x * EBLK;
    const int end  = (base + EBLK < NEDGES) ? base + EBLK : NEDGES;
    for (int e = base + threadIdx.x; e < end; e += 256)
        atomicAdd(&hist[dst[e] >> 7], 1u);
    __syncthreads();
    for (int i = threadIdx.x; i < NBUCK; i += 256)
        counts[(size_t)blockIdx.x * NBUCK + i] = hist[i];
}

__global__ __launch_bounds__(256) void col_prefix_kernel(
        unsigned* __restrict__ counts, unsigned* __restrict__ totals) {
    const int b = blockIdx.x * 256 + threadIdx.x;
    if (b >= NBUCK) return;
    unsigned s = 0;
    for (int i = 0; i < NBLK; ++i) {
        const unsigned c = counts[(size_t)i * NBUCK + b];
        counts[(size_t)i * NBUCK + b] = s;
        s += c;
    }
    totals[b] = s;
}

__global__ __launch_bounds__(1024) void base_scan_kernel(
        const unsigned* __restrict__ totals, unsigned* __restrict__ bucketbase) {
    const int tid = threadIdx.x;
    const unsigned v = (tid < NBUCK) ? totals[tid] : 0u;
    const int lane = tid & 63, w = tid >> 6;
    unsigned s = v;
    #pragma unroll
    for (int o = 1; o < 64; o <<= 1) {
        unsigned t = (unsigned)__shfl_up((int)s, o);
        if (lane >= o) s += t;
    }
    __shared__ unsigned wsum[16];
    if (lane == 63) wsum[w] = s;
    __syncthreads();
    unsigned add = 0;
    #pragma unroll
    for (int j = 0; j < 15; ++j) if (w > j) add += wsum[j];
    if (tid < NBUCK) bucketbase[tid] = s + add - v;
    if (tid == NBUCK - 1) bucketbase[NBUCK] = s + add;   // == NEDGES
}

__global__ __launch_bounds__(256) void bin_scatter_kernel(
        const int* __restrict__ src, const int* __restrict__ dst,
        const unsigned* __restrict__ counts, const unsigned* __restrict__ bucketbase,
        unsigned* __restrict__ pairs) {
    __shared__ unsigned off[NBUCK];
    for (int i = threadIdx.x; i < NBUCK; i += 256)
        off[i] = bucketbase[i] + counts[(size_t)blockIdx.x * NBUCK + i];
    __syncthreads();
    const int base = blockIdx.x * EBLK;
    const int end  = (base + EBLK < NEDGES) ? base + EBLK : NEDGES;
    for (int e = base + threadIdx.x; e < end; e += 256) {
        const int d = dst[e];
        const unsigned pos = atomicAdd(&off[d >> 7], 1u);
        pairs[pos] = ((unsigned)(d & 127) << 17) | (unsigned)src[e];
    }
}

__global__ __launch_bounds__(256) void bucket_csr_kernel(
        const unsigned* __restrict__ pairs, const unsigned* __restrict__ bucketbase,
        int* __restrict__ row_start, int* __restrict__ csr_src) {
    __shared__ unsigned deg[128], rs[128], fill[128];
    const int b = blockIdx.x;
    const unsigned seg0 = bucketbase[b], seg1 = bucketbase[b + 1];
    const int t = threadIdx.x;
    if (t < 128) deg[t] = 0;
    __syncthreads();
    for (unsigned i = seg0 + t; i < seg1; i += 256)
        atomicAdd(&deg[pairs[i] >> 17], 1u);
    __syncthreads();
    if (t < 128) rs[t] = deg[t];
    __syncthreads();
    #pragma unroll
    for (int o = 1; o < 128; o <<= 1) {           // Hillis-Steele inclusive
        unsigned tmp = 0;
        if (t < 128 && t >= o) tmp = rs[t - o];
        __syncthreads();
        if (t < 128) rs[t] += tmp;
        __syncthreads();
    }
    if (t < 128) {
        const unsigned excl = rs[t] - deg[t];
        fill[t] = excl;
        const int node = b * 128 + t;
        if (node < NNODES) row_start[node] = (int)(seg0 + excl);
    }
    __syncthreads();
    for (unsigned i = seg0 + t; i < seg1; i += 256) {
        const unsigned p = pairs[i];
        const unsigned r = atomicAdd(&fill[p >> 17], 1u);
        csr_src[seg0 + r] = (int)(p & 0x1ffffu);
    }
    if (b == 0 && t == 0) row_start[NNODES] = NEDGES;
}

// ---------------------------------------------------------------------------
// per-node attention halves: a_src[n] = x[n]·Wa[0:128]; a_dst[n] = x[n]·Wa[128:]+ba
// ---------------------------------------------------------------------------
__global__ __launch_bounds__(256) void node_dots_kernel(
        const unsigned short* __restrict__ xb, const float* __restrict__ Wa,
        const float* __restrict__ ba,
        float* __restrict__ a_src, float* __restrict__ a_dst) {
    const int n = (blockIdx.x * blockDim.x + threadIdx.x) >> 6;
    if (n >= NNODES) return;
    const int lane = threadIdx.x & 63;
    const unsigned u = *(const unsigned*)(xb + (size_t)n * DIM + lane * 2);
    const float x0 = bf_lo(u), x1 = bf_hi(u);
    const float2 wlo = *(const float2*)(Wa + lane * 2);
    const float2 whi = *(const float2*)(Wa + DIM + lane * 2);
    float ps = x0 * wlo.x + x1 * wlo.y;
    float pd = x0 * whi.x + x1 * whi.y;
    #pragma unroll
    for (int o = 32; o; o >>= 1) { ps += __shfl_xor(ps, o); pd += __shfl_xor(pd, o); }
    if (lane == 0) { a_src[n] = ps; a_dst[n] = pd + ba[0]; }
}

// ---------------------------------------------------------------------------
// pull aggregation, quarter-wave (16 lanes = one node, 16B/lane), fused att
// ---------------------------------------------------------------------------
__global__ __launch_bounds__(256) void pull_agg_kernel(
        const int* __restrict__ row_start, const int* __restrict__ csr_src,
        const float* __restrict__ a_src, const float* __restrict__ a_dst,
        const unsigned short* __restrict__ xb, unsigned short* __restrict__ aggb) {
    const int n = blockIdx.x * 16 + (threadIdx.x >> 4);
    if (n >= NNODES) return;
    const int lane = threadIdx.x & 63;
    const int sub  = lane & 15;        // position within quarter
    const int qb   = lane & 48;        // quarter base lane
    const int beg = row_start[n], end = row_start[n + 1];
    const float adst = a_dst[n];

    float a0 = 0, a1 = 0, a2 = 0, a3 = 0, a4 = 0, a5 = 0, a6 = 0, a7 = 0;

    for (int base = beg; base < end; base += 16) {
        const int rem = end - base;
        const int cnt = rem < 16 ? rem : 16;
        int   idx_l = 0;
        float att_l = 0.0f;
        if (sub < cnt) {
            idx_l = csr_src[base + sub];
            att_l = 1.0f / (1.0f + __expf(-(a_src[idx_l] + adst)));
        }
        int i = 0;
        for (; i + 3 < cnt; i += 4) {
            const int   s0 = __shfl(idx_l, qb + i);
            const int   s1 = __shfl(idx_l, qb + i + 1);
            const int   s2 = __shfl(idx_l, qb + i + 2);
            const int   s3 = __shfl(idx_l, qb + i + 3);
            const float w0 = __shfl(att_l, qb + i);
            const float w1 = __shfl(att_l, qb + i + 1);
            const float w2 = __shfl(att_l, qb + i + 2);
            const float w3 = __shfl(att_l, qb + i + 3);
            const uint4 u0 = *(const uint4*)(xb + (size_t)s0 * DIM + sub * 8);
            const uint4 u1 = *(const uint4*)(xb + (size_t)s1 * DIM + sub * 8);
            const uint4 u2 = *(const uint4*)(xb + (size_t)s2 * DIM + sub * 8);
            const uint4 u3 = *(const uint4*)(xb + (size_t)s3 * DIM + sub * 8);
            a0 += bf_lo(u0.x) * w0 + bf_lo(u1.x) * w1 + bf_lo(u2.x) * w2 + bf_lo(u3.x) * w3;
            a1 += bf_hi(u0.x) * w0 + bf_hi(u1.x) * w1 + bf_hi(u2.x) * w2 + bf_hi(u3.x) * w3;
            a2 += bf_lo(u0.y) * w0 + bf_lo(u1.y) * w1 + bf_lo(u2.y) * w2 + bf_lo(u3.y) * w3;
            a3 += bf_hi(u0.y) * w0 + bf_hi(u1.y) * w1 + bf_hi(u2.y) * w2 + bf_hi(u3.y) * w3;
            a4 += bf_lo(u0.z) * w0 + bf_lo(u1.z) * w1 + bf_lo(u2.z) * w2 + bf_lo(u3.z) * w3;
            a5 += bf_hi(u0.z) * w0 + bf_hi(u1.z) * w1 + bf_hi(u2.z) * w2 + bf_hi(u3.z) * w3;
            a6 += bf_lo(u0.w) * w0 + bf_lo(u1.w) * w1 + bf_lo(u2.w) * w2 + bf_lo(u3.w) * w3;
            a7 += bf_hi(u0.w) * w0 + bf_hi(u1.w) * w1 + bf_hi(u2.w) * w2 + bf_hi(u3.w) * w3;
        }
        for (; i < cnt; ++i) {
            const int   s = __shfl(idx_l, qb + i);
            const float w = __shfl(att_l, qb + i);
            const uint4 u = *(const uint4*)(xb + (size_t)s * DIM + sub * 8);
            a0 += bf_lo(u.x) * w;  a1 += bf_hi(u.x) * w;
            a2 += bf_lo(u.y) * w;  a3 += bf_hi(u.y) * w;
            a4 += bf_lo(u.z) * w;  a5 += bf_hi(u.z) * w;
            a6 += bf_lo(u.w) * w;  a7 += bf_hi(u.w) * w;
        }
    }

    uint4 o;
    o.x = ((unsigned)f2bf(a1) << 16) | (unsigned)f2bf(a0);
    o.y = ((unsigned)f2bf(a3) << 16) | (unsigned)f2bf(a2);
    o.z = ((unsigned)f2bf(a5) << 16) | (unsigned)f2bf(a4);
    o.w = ((unsigned)f2bf(a7) << 16) | (unsigned)f2bf(a6);
    *(uint4*)(aggb + (size_t)n * DIM + sub * 8) = o;
}

// ---------------------------------------------------------------------------
// x_new = relu([x || agg] @ Wg + bg) via bf16 MFMA (async LDS A-staging)
// ---------------------------------------------------------------------------
__global__ __launch_bounds__(256) void gemm_mfma_kernel(
        const unsigned short* __restrict__ xb, const unsigned short* __restrict__ aggb,
        const unsigned short* __restrict__ bfr, const float* __restrict__ bg,
        float* __restrict__ xout_f32, unsigned short* __restrict__ xout_bf,
        int write_f32, int write_bf) {
    __shared__ unsigned short At[2][128 * 128];     // 64 KB

    const int tid  = threadIdx.x;
    const int lane = tid & 63;
    const int wid  = tid >> 6;
    const int mbase = blockIdx.x * 128;

    #pragma unroll
    for (int h = 0; h < 2; ++h) {
        const unsigned short* src = h ? aggb : xb;
        #pragma unroll
        for (int i = 0; i < 8; ++i) {
            const int lrow = i * 16 + wid * 4 + (lane >> 4);       // 0..127
            const int c    = (lane & 15) ^ (lrow & 7);             // src chunk
            const unsigned short* g = src + (size_t)(mbase + lrow) * DIM + c * 8;
            async16(g, &At[h][(i * 16 + wid * 4) * 128]);          // uniform base
        }
    }

    const int waveM = wid >> 1, waveN = wid & 1;
    const int l16 = lane & 15, kq = lane >> 4;
    const unsigned short* bfw = bfr + (size_t)(waveN * 8) * 4 * 64 * 8;

    f32x4 acc[4][4] = {};
    short8 bcur[4], bnxt[4];

    asm volatile("s_waitcnt vmcnt(8)" ::: "memory");
    __builtin_amdgcn_s_barrier();

    #pragma unroll
    for (int nf = 0; nf < 4; ++nf)
        bcur[nf] = *(const short8*)(bfw + ((size_t)(0 * 4 + nf) * 64 + lane) * 8);

    #pragma unroll
    for (int ks = 0; ks < 8; ++ks) {
        if (ks == 4) {
            asm volatile("s_waitcnt vmcnt(0)" ::: "memory");
            __builtin_amdgcn_s_barrier();
        }
        if (ks < 7) {
            #pragma unroll
            for (int nf = 0; nf < 4; ++nf)
                bnxt[nf] = *(const short8*)(bfw + ((size_t)((ks + 1) * 4 + nf) * 64 + lane) * 8);
        }
        const int h = ks >> 2, ksl = ks & 3;
        short8 a[4];
        #pragma unroll
        for (int mf = 0; mf < 4; ++mf) {
            const int row   = waveM * 64 + mf * 16 + l16;
            const int chunk = (ksl * 4 + kq) ^ (row & 7);
            a[mf] = *(const short8*)&At[h][row * 128 + chunk * 8];
        }
        #pragma unroll
        for (int mf = 0; mf < 4; ++mf)
            #pragma unroll
            for (int nf = 0; nf < 4; ++nf)
                acc[mf][nf] = __builtin_amdgcn_mfma_f32_16x16x32_bf16(
                    a[mf], bcur[nf], acc[mf][nf], 0, 0, 0);
        if (ks < 7) {
            #pragma unroll
            for (int nf = 0; nf < 4; ++nf) bcur[nf] = bnxt[nf];
        }
    }

    const int rsub = kq * 4;
    #pragma unroll
    for (int nf = 0; nf < 4; ++nf) {
        const int col  = waveN * 64 + nf * 16 + l16;
        const float bias = bg[col];
        #pragma unroll
        for (int mf = 0; mf < 4; ++mf) {
            #pragma unroll
            for (int j = 0; j < 4; ++j) {
                const int row = mbase + waveM * 64 + mf * 16 + rsub + j;
                const float v = fmaxf(acc[mf][nf][j] + bias, 0.0f);
                if (write_f32 && row < NNODES)
                    xout_f32[(size_t)row * DIM + col] = v;
                if (write_bf) {
                    const unsigned short b = f2bf(v);
                    const unsigned pb = (unsigned)(unsigned short)__shfl_xor((int)b, 1);
                    if (!(l16 & 1) && row < NNODES) {
                        const unsigned packed = (unsigned)b | (pb << 16);
                        *(unsigned*)(xout_bf + (size_t)row * DIM + col) = packed;
                    }
                }
            }
        }
    }
}

// ---------------------------------------------------------------------------
extern "C" void kernel_launch(void* const* d_in, const int* in_sizes, int n_in,
                              void* d_out, int out_size, void* d_ws, size_t ws_size,
                              hipStream_t stream) {
    const int*   edge = (const int*)d_in[0];       // [2, E]
    const float* ue   = (const float*)d_in[1];
    const float* ie   = (const float*)d_in[2];
    const float* Wa   = (const float*)d_in[3];     // [3, 256, 1]
    const float* ba   = (const float*)d_in[4];     // [3, 1]
    const float* Wg   = (const float*)d_in[5];     // [3, 256, 128]
    const float* bg   = (const float*)d_in[6];     // [3, 128]

    const int* src = edge;
    const int* dst = edge + NEDGES;

    float* x = (float*)d_out;                      // final f32 output

    // ---- workspace layout ----
    unsigned short* xb   = (unsigned short*)d_ws;            // NPAD*128 bf16
    unsigned short* aggb = xb + (size_t)NPAD * DIM;          // NPAD*128 bf16
    unsigned short* bfr  = aggb + (size_t)NPAD * DIM;        // 3*32768 bf16
    float* a_src      = (float*)(bfr + NLAYERS * 32768);     // NPAD f
    float* a_dst      = a_src + NPAD;                        // NPAD f
    int*   row_start  = (int*)(a_dst + NPAD);                // NPAD+256 i
    int*   csr_src    = row_start + NPAD + 256;              // NEDGES i
    unsigned* pairs   = (unsigned*)(csr_src + NEDGES);       // NEDGES u
    unsigned* counts  = pairs + NEDGES;                      // NBLK*NBUCK u
    unsigned* totals  = counts + (size_t)NBLK * NBUCK;       // NBUCK u
    unsigned* bbase   = totals + NBUCK;                      // NBUCK+1 u

    concat_kernel<<<(NNODES * DIM / 4 + 255) / 256, 256, 0, stream>>>(ue, ie, xb);
    wg_conv_kernel<<<(NLAYERS * 4096 + 255) / 256, 256, 0, stream>>>(Wg, bfr);

    // ---- binned CSR build ----
    bin_count_kernel<<<NBLK, 256, 0, stream>>>(dst, counts);
    col_prefix_kernel<<<(NBUCK + 255) / 256, 256, 0, stream>>>(counts, totals);
    base_scan_kernel<<<1, 1024, 0, stream>>>(totals, bbase);
    bin_scatter_kernel<<<NBLK, 256, 0, stream>>>(src, dst, counts, bbase, pairs);
    bucket_csr_kernel<<<NBUCK, 256, 0, stream>>>(pairs, bbase, row_start, csr_src);

    const int gemm_blocks = (NNODES + 127) / 128;            // 782
    const int pull_blocks = (NNODES + 15) / 16;              // 6250
    for (int l = 0; l < NLAYERS; ++l) {
        node_dots_kernel<<<(NNODES * 64 + 255) / 256, 256, 0, stream>>>(
            xb, Wa + (size_t)l * 256, ba + l, a_src, a_dst);
        pull_agg_kernel<<<pull_blocks, 256, 0, stream>>>(
            row_start, csr_src, a_src, a_dst, xb, aggb);
        const int last = (l == NLAYERS - 1);
        gemm_mfma_kernel<<<gemm_blocks, 256, 0, stream>>>(
            xb, aggb, bfr + (size_t)l * 32768, bg + (size_t)l * DIM,
            x, xb, last ? 1 : 0, last ? 0 : 1);
    }
}